// Round 8
// baseline (419.296 us; speedup 1.0000x reference)
//
#include <hip/hip_runtime.h>
#include <hip/hip_bf16.h>
#include <math.h>

#define HH 256
#define WW 256
#define AREA 65536
#define CIN 16
#define NS 4
#define CSUR 128
#define NEXT 144
#define NPAIR 45

typedef __attribute__((ext_vector_type(8))) short bf16x8;
typedef __attribute__((ext_vector_type(4))) float f32x4;

__constant__ int c_dy[8] = {-1,-1,-1, 0, 0, 1, 1, 1};
__constant__ int c_dx[8] = {-1, 0, 1,-1, 1,-1, 0, 1};

__device__ constexpr int CTI[NPAIR] = {
    0, 1,1, 2,2,2, 3,3,3,3, 4,4,4,4,4,
    5,5,5,5,5,5, 6,6,6,6,6,6,6, 7,7,7,7,7,7,7,7,
    8,8,8,8,8,8,8,8,8};
__device__ constexpr int CTJ[NPAIR] = {
    0, 0,1, 0,1,2, 0,1,2,3, 0,1,2,3,4,
    0,1,2,3,4,5, 0,1,2,3,4,5,6, 0,1,2,3,4,5,6,7,
    0,1,2,3,4,5,6,7,8};

__device__ __forceinline__ int refl(int v) {
    return v < 0 ? -v : (v > 255 ? 510 - v : v);
}

__device__ __forceinline__ unsigned pkbf(float a, float b) {
    __hip_bfloat162 h = __float22bfloat162_rn(make_float2(a, b));
    unsigned r;
    __builtin_memcpy(&r, &h, 4);
    return r;
}

// ---------------------------------------------------------------------------
// K1: diff Gram via compensated bf16 MFMA, 2 waves/block, K=32 tiles.
// LDS layout: per view tt (9), rows c (16): paired-row lines of 256B.
//   phys16(c,L) = (c>>1)*16 + (((L<<1)|(c&1)) ^ (((c>>1)&7)<<1)); uidx=phys16*4
//   L: 0..3 = hi px-chunks (8 px each), 4..7 = lo.
// grid (64 chunks x 4 rows, s=4, b=4), 128 threads. 8 partial buffers (chunk&7).
// ---------------------------------------------------------------------------
__global__ __launch_bounds__(128) void k1_gram(const float* __restrict__ cen,
                                               float* __restrict__ part) {
    const int chunk = blockIdx.x;
    const int s = blockIdx.y;
    const int b = blockIdx.z;
    const int d = 1 << s;
    const int t = threadIdx.x;
    const int lane = t & 63, wid = t >> 6;
    const int lr = lane & 15, lg = lane >> 4;
    const int cin = t >> 3, p0 = t & 7;
    const int y0 = chunk * 4;
    const float* base = cen + ((size_t)b * CIN + cin) * AREA;

    __shared__ unsigned lds[2][4608];   // 2 x 18,432 B

    // write offsets (uint idx within view block of 512 uints)
    const int cb16 = (cin >> 1) * 16, codd = cin & 1, cq = (cin >> 1) << 1;
#define PHI(L) (cb16 + ((((L) << 1) | codd) ^ cq))
    const int wHiA = PHI(p0 >> 2) * 4 + (p0 & 3);
    const int wLoA = PHI(4 + (p0 >> 2)) * 4 + (p0 & 3);
    const int wHiB = PHI(2 + (p0 >> 2)) * 4 + (p0 & 3);
    const int wLoB = PHI(6 + (p0 >> 2)) * 4 + (p0 & 3);
#undef PHI
    // read offsets (uint idx within view block)
    const int rb16 = (lr >> 1) * 16, rodd = lr & 1, rq = (lr >> 1) << 1;
    const int rHi = (rb16 + ((((lg) << 1) | rodd) ^ rq)) * 4;
    const int rLo = (rb16 + ((((4 + lg) << 1) | rodd) ^ rq)) * 4;

    const int xA0 = 2 * p0;

    auto stage = [&](unsigned* buf, int yy, int x0) {
        const float* rowy = base + yy * WW;
        const int xA = x0 + xA0, xB = xA + 16;
        const float2 cA = *(const float2*)(rowy + xA);
        const float2 cB = *(const float2*)(rowy + xB);
        {
            unsigned h = pkbf(cA.x, cA.y);
            buf[wHiA] = h;
            buf[wLoA] = pkbf(cA.x - __builtin_bit_cast(float, h << 16),
                             cA.y - __builtin_bit_cast(float, h & 0xFFFF0000u));
            h = pkbf(cB.x, cB.y);
            buf[wHiB] = h;
            buf[wLoB] = pkbf(cB.x - __builtin_bit_cast(float, h << 16),
                             cB.y - __builtin_bit_cast(float, h & 0xFFFF0000u));
        }
#pragma unroll
        for (int kk = 0; kk < 8; ++kk) {
            const int ys = refl(yy + c_dy[kk] * d);
            const float* rows = base + ys * WW;
            const int off = c_dx[kk] * d;
            float2 sA, sB;
            const int xa = xA + off;
            if (xa >= 0 && xa <= 254) sA = *(const float2*)(rows + xa);
            else { sA.x = rows[refl(xa)]; sA.y = rows[refl(xa + 1)]; }
            const int xb2 = xB + off;
            if (xb2 >= 0 && xb2 <= 254) sB = *(const float2*)(rows + xb2);
            else { sB.x = rows[refl(xb2)]; sB.y = rows[refl(xb2 + 1)]; }
            unsigned* vb = buf + (kk + 1) * 512;
            float da = sA.x - cA.x, db = sA.y - cA.y;
            unsigned h = pkbf(da, db);
            vb[wHiA] = h;
            vb[wLoA] = pkbf(da - __builtin_bit_cast(float, h << 16),
                            db - __builtin_bit_cast(float, h & 0xFFFF0000u));
            da = sB.x - cB.x; db = sB.y - cB.y;
            h = pkbf(da, db);
            vb[wHiB] = h;
            vb[wLoB] = pkbf(da - __builtin_bit_cast(float, h << 16),
                            db - __builtin_bit_cast(float, h & 0xFFFF0000u));
        }
    };

    f32x4 acc[23];
#pragma unroll
    for (int i = 0; i < 23; ++i) acc[i] = (f32x4){0.f, 0.f, 0.f, 0.f};

    stage(lds[0], y0, 0);
    __syncthreads();

    for (int ph = 0; ph < 32; ++ph) {
        const int cur = ph & 1;
        if (ph + 1 < 32) {
            stage(lds[cur ^ 1], y0 + ((ph + 1) >> 3), ((ph + 1) & 7) * 32);
        }
        const unsigned* m = lds[cur];
        bf16x8 fh[9], fl[9];
#pragma unroll
        for (int tt = 0; tt < 9; ++tt) {
            fh[tt] = *(const bf16x8*)(m + tt * 512 + rHi);
            fl[tt] = *(const bf16x8*)(m + tt * 512 + rLo);
        }
        if (wid == 0) {
#pragma unroll
            for (int p = 0; p < 23; ++p) {
                const int i = CTI[p], j = CTJ[p];
                acc[p] = __builtin_amdgcn_mfma_f32_16x16x32_bf16(fh[i], fh[j], acc[p], 0, 0, 0);
                acc[p] = __builtin_amdgcn_mfma_f32_16x16x32_bf16(fh[i], fl[j], acc[p], 0, 0, 0);
                acc[p] = __builtin_amdgcn_mfma_f32_16x16x32_bf16(fl[i], fh[j], acc[p], 0, 0, 0);
            }
        } else {
#pragma unroll
            for (int p = 0; p < 22; ++p) {
                const int i = CTI[23 + p], j = CTJ[23 + p];
                acc[p] = __builtin_amdgcn_mfma_f32_16x16x32_bf16(fh[i], fh[j], acc[p], 0, 0, 0);
                acc[p] = __builtin_amdgcn_mfma_f32_16x16x32_bf16(fh[i], fl[j], acc[p], 0, 0, 0);
                acc[p] = __builtin_amdgcn_mfma_f32_16x16x32_bf16(fl[i], fh[j], acc[p], 0, 0, 0);
            }
        }
        __syncthreads();
    }

    float* tb = part + (size_t)((chunk & 7) * 16 + b * 4 + s) * 20736;
    const int np = (wid == 0) ? 23 : 22;
    const int pb = (wid == 0) ? 0 : 23;
#pragma unroll
    for (int p = 0; p < 23; ++p) {
        if (p < np) {
            const int gi0 = CTI[pb + p] * 16 + lg * 4;
            const int gj  = CTJ[pb + p] * 16 + lr;
            const f32x4 a = acc[p];
#pragma unroll
            for (int r = 0; r < 4; ++r)
                atomicAdd(&tb[(gi0 + r) * 144 + gj], a[r]);
        }
    }
}

// ---------------------------------------------------------------------------
// K1c: sum 8 partials + mirror -> Gfull ; A = q_w·G ; normQ. grid (4,4).
// ---------------------------------------------------------------------------
__global__ __launch_bounds__(256) void k1c(const float* __restrict__ part,
                                           const float* __restrict__ q_w,
                                           float* __restrict__ Gfull,
                                           float* __restrict__ A,
                                           float* __restrict__ normQ) {
    const int s = blockIdx.x, b = blockIdx.y, bs = b * 4 + s;
    const int t = threadIdx.x;
    __shared__ float Ts[144][148];
    for (int e = t; e < 20736; e += 256) {
        const int i = e / 144, j = e - i * 144;
        if (i >= j) {
            float v = 0.f;
#pragma unroll
            for (int c = 0; c < 8; ++c)
                v += part[(size_t)(c * 16 + bs) * 20736 + e];
            Ts[i][j] = v;
            Ts[j][i] = v;
        }
    }
    __syncthreads();
    float* go = Gfull + (size_t)bs * 20736;
    for (int e = t; e < 20736; e += 256) {
        const int i = e / 144, j = e - i * 144;
        go[e] = Ts[i][j];
    }
    for (int e = t; e < 8192; e += 256) {
        const int jq = e >> 7, cp = e & 127;
        const float* qrow = q_w + jq * 16;
        const float* trow = &Ts[16 + cp][0];
        float a = 0.f;
#pragma unroll
        for (int cin = 0; cin < 16; ++cin) a = fmaf(qrow[cin], trow[cin], a);
        A[((size_t)bs * 64 + jq) * 128 + cp] = a;
    }
    if (s == 0 && t < 64) {
        float nq = 0.f;
#pragma unroll
        for (int c1 = 0; c1 < 16; ++c1) {
            float ra = 0.f;
#pragma unroll
            for (int c2 = 0; c2 < 16; ++c2)
                ra = fmaf(q_w[t * 16 + c2], Ts[c1][c2], ra);
            nq = fmaf(q_w[t * 16 + c1], ra, nq);
        }
        normQ[b * 64 + t] = nq;
    }
}

// ---------------------------------------------------------------------------
// K2n: normK[bs][ck] = k_row·H·k_rowT, split (32 ck) x (64 i) per block.
// grid (ckg=4, bs=16, ih=2), 256 threads.
// ---------------------------------------------------------------------------
__global__ __launch_bounds__(256) void k2n(const float* __restrict__ k_w,
                                           const float* __restrict__ Gfull,
                                           float* __restrict__ normK) {
    const int ckg = blockIdx.x, bs = blockIdx.y, ih = blockIdx.z;
    const int s = bs & 3;
    const int t = threadIdx.x;
    __shared__ float kS[32][129];
    __shared__ float Hs[64][129];
    __shared__ float red[256];
    for (int e = t; e < 4096; e += 256) {
        const int r = e >> 7, j = e & 127;
        kS[r][j] = k_w[(size_t)(s * 128 + ckg * 32 + r) * 128 + j];
    }
    for (int e = t; e < 8192; e += 256) {
        const int r = e >> 7, j = e & 127;
        Hs[r][j] = Gfull[(size_t)bs * 20736 + (16 + ih * 64 + r) * 144 + 16 + j];
    }
    __syncthreads();
    const int ckl = t & 31, p = t >> 5;
    float m[8];
#pragma unroll
    for (int i = 0; i < 8; ++i) m[i] = 0.f;
    for (int j = 0; j < 128; ++j) {
        const float kv = kS[ckl][j];
#pragma unroll
        for (int i = 0; i < 8; ++i) m[i] = fmaf(Hs[p * 8 + i][j], kv, m[i]);
    }
    float prt = 0.f;
#pragma unroll
    for (int i = 0; i < 8; ++i)
        prt = fmaf(kS[ckl][ih * 64 + p * 8 + i], m[i], prt);
    red[t] = prt;
    __syncthreads();
    if (t < 32) {
        float s8 = 0.f;
#pragma unroll
        for (int q = 0; q < 8; ++q) s8 += red[q * 32 + t];
        atomicAdd(&normK[(size_t)bs * 128 + ckg * 32 + t], s8);
    }
}

// ---------------------------------------------------------------------------
// K2b: scores -> instance norm -> softmax -> wEff. grid (a=4, b=4), 256 thr.
// ---------------------------------------------------------------------------
__global__ __launch_bounds__(256) void k2b(const float* __restrict__ k_w,
                                           const float* __restrict__ v_w,
                                           const float* __restrict__ A,
                                           const float* __restrict__ normK,
                                           const float* __restrict__ normQ,
                                           float* __restrict__ wEff) {
    const int a = blockIdx.x, b = blockIdx.y;
    const int t = threadIdx.x;
    __shared__ float AS[4][16][128];
    __shared__ float kv[4][32][132];
    __shared__ float sc[2048];
    __shared__ float red[256];
    __shared__ float rowred[256];
    __shared__ float rowmax[16], rowsum[16];
    __shared__ float s_mu, s_rs;

    for (int idx = t; idx < 8192; idx += 256) {
        const int sk = idx >> 11, rr = (idx >> 7) & 15, cp = idx & 127;
        const int jq = (rr & 3) * 16 + 4 * a + (rr >> 2);
        AS[sk][rr][cp] = A[((size_t)(b * 4 + sk) * 64 + jq) * 128 + cp];
    }
    for (int idx = t; idx < 16384; idx += 256) {
        const int sk = idx >> 12, ckl = (idx >> 7) & 31, cp = idx & 127;
        kv[sk][ckl][cp] = k_w[((size_t)sk * 128 + 32 * a + ckl) * 128 + cp];
    }
    __syncthreads();
    for (int e = t; e < 2048; e += 256) {
        const int r = e >> 7, dd = e & 127;
        const int sk = dd & 3, ckl = dd >> 2;
        const float4* Ar = (const float4*)(&AS[sk][r][0]);
        const float4* kr = (const float4*)(&kv[sk][ckl][0]);
        float4 pv = {0.f, 0.f, 0.f, 0.f};
#pragma unroll 8
        for (int jj = 0; jj < 32; ++jj) {
            const float4 h = Ar[jj], k4 = kr[jj];
            pv.x = fmaf(h.x, k4.x, pv.x);
            pv.y = fmaf(h.y, k4.y, pv.y);
            pv.z = fmaf(h.z, k4.z, pv.z);
            pv.w = fmaf(h.w, k4.w, pv.w);
        }
        const float dot = pv.x + pv.y + pv.z + pv.w;
        const int jq = (r & 3) * 16 + 4 * a + (r >> 2);
        const float qn = fmaxf(sqrtf(fmaxf(normQ[b * 64 + jq], 0.f)), 1e-12f);
        const float kn = fmaxf(sqrtf(fmaxf(normK[(size_t)(b * 4 + sk) * 128 + 32 * a + ckl], 0.f)), 1e-12f);
        sc[e] = dot / (qn * kn * 256.0f);
    }
    __syncthreads();
    for (int idx = t; idx < 16384; idx += 256) {
        const int sk = idx >> 12, m = (idx >> 7) & 31, cp = idx & 127;
        kv[sk][m][cp] = v_w[((size_t)sk * 128 + 32 * a + m) * 128 + cp];
    }
    {
        float p = 0.f;
        for (int e = t; e < 2048; e += 256) p += sc[e];
        red[t] = p; __syncthreads();
        for (int off = 128; off > 0; off >>= 1) {
            if (t < off) red[t] += red[t + off];
            __syncthreads();
        }
        if (t == 0) s_mu = red[0] * (1.f / 2048.f);
        __syncthreads();
    }
    {
        const float mu = s_mu;
        float p = 0.f;
        for (int e = t; e < 2048; e += 256) { const float z = sc[e] - mu; p += z * z; }
        red[t] = p; __syncthreads();
        for (int off = 128; off > 0; off >>= 1) {
            if (t < off) red[t] += red[t + off];
            __syncthreads();
        }
        if (t == 0) s_rs = rsqrtf(red[0] * (1.f / 2048.f) + 1e-5f);
        __syncthreads();
    }
    const float mu = s_mu, rs = s_rs;
    const int r = t >> 4, l = t & 15;
    {
        float m = -1e30f;
#pragma unroll
        for (int j = 0; j < 8; ++j) {
            const float z = (sc[r * 128 + l + j * 16] - mu) * rs;
            m = fmaxf(m, z);
        }
        rowred[t] = m; __syncthreads();
        if (l == 0) {
            float m2 = rowred[r * 16];
            for (int j = 1; j < 16; ++j) m2 = fmaxf(m2, rowred[r * 16 + j]);
            rowmax[r] = m2;
        }
        __syncthreads();
    }
    {
        float p = 0.f;
#pragma unroll
        for (int j = 0; j < 8; ++j) {
            const float z = (sc[r * 128 + l + j * 16] - mu) * rs;
            p += expf(z - rowmax[r]);
        }
        rowred[t] = p; __syncthreads();
        if (l == 0) {
            float p2 = 0.f;
            for (int j = 0; j < 16; ++j) p2 += rowred[r * 16 + j];
            rowsum[r] = p2;
        }
        __syncthreads();
    }
    {
        float vals[8];
#pragma unroll
        for (int j = 0; j < 8; ++j) {
            const float z = (sc[r * 128 + l + j * 16] - mu) * rs;
            vals[j] = expf(z - rowmax[r]) / rowsum[r];
        }
        __syncthreads();
#pragma unroll
        for (int j = 0; j < 8; ++j) sc[r * 128 + l + j * 16] = vals[j];
        __syncthreads();
    }
    for (int e = t; e < 8192; e += 256) {
        const int sk = e >> 11, r2 = (e >> 7) & 15, cp = e & 127;
        float w = 0.f;
#pragma unroll
        for (int m = 0; m < 32; ++m)
            w = fmaf(sc[r2 * 128 + 4 * m + sk], kv[sk][m][cp], w);
        wEff[((size_t)(b * 4 + sk) * 64 + (a * 16 + r2)) * 128 + cp] = w;
    }
}

// ---------------------------------------------------------------------------
// K2c: wFinal. grid (s=4, b=4), 256 threads.
// ---------------------------------------------------------------------------
__global__ __launch_bounds__(256) void k2c(const float* __restrict__ out_w,
                                           const float* __restrict__ bn_gamma,
                                           const float* __restrict__ bn_var,
                                           const float* __restrict__ wEff,
                                           float* __restrict__ wFinal) {
    const int s = blockIdx.x, b = blockIdx.y;
    const int t = threadIdx.x;
    __shared__ float we[64][128];
    for (int idx = t; idx < 8192; idx += 256) {
        const int j = idx >> 7, cp = idx & 127;
        we[j][cp] = wEff[((size_t)(b * 4 + s) * 64 + j) * 128 + cp];
    }
    __syncthreads();
    for (int e = t; e < 2048; e += 256) {
        const int o = e >> 7, cp = e & 127;
        float w = 0.f;
#pragma unroll 16
        for (int j = 0; j < 64; ++j)
            w = fmaf(out_w[o * 64 + j], we[j][cp], w);
        const float scale = bn_gamma[o] * rsqrtf(bn_var[o] + 1e-5f);
        wFinal[((size_t)(b * 4 + s) * 16 + o) * 128 + cp] = w * scale;
    }
}

// ---------------------------------------------------------------------------
// K3: out = relu( sum_s wFinal_s·sur_s + bias ). grid (128, b=4), 256 thr.
// ---------------------------------------------------------------------------
__global__ __launch_bounds__(256) void k3_out(const float* __restrict__ cen,
                                              const float* __restrict__ wFinal,
                                              const float* __restrict__ bn_gamma,
                                              const float* __restrict__ bn_beta,
                                              const float* __restrict__ bn_mean,
                                              const float* __restrict__ bn_var,
                                              float* __restrict__ out) {
    const int by = blockIdx.x;
    const int b  = blockIdx.y;
    const int t  = threadIdx.x;
    __shared__ __align__(16) float wf[NS * CSUR * 16];
    __shared__ __align__(16) float wc[16 * 16];

    for (int e = t; e < NS * CSUR * 16; e += 256) {
        const int s = e >> 11, cp = (e >> 4) & 127, o = e & 15;
        wf[e] = wFinal[((size_t)(b * NS + s) * 16 + o) * CSUR + cp];
    }
    __syncthreads();
    {
        const int cin = t >> 4, o = t & 15;
        float sum = 0.f;
#pragma unroll
        for (int s = 0; s < NS; ++s)
#pragma unroll
            for (int k = 0; k < 8; ++k)
                sum += wf[(s * CSUR + k * 16 + cin) * 16 + o];
        wc[cin * 16 + o] = sum;
    }
    __syncthreads();

    const int x0 = t & 127;
    const int x1 = x0 + 128;
    const int y  = by * 2 + (t >> 7);
    const float* cb = cen + (size_t)b * CIN * AREA;

    float acc0[16], acc1[16];
#pragma unroll
    for (int o = 0; o < 16; ++o) { acc0[o] = 0.f; acc1[o] = 0.f; }

    for (int s = 0; s < NS; ++s) {
        const int d = 1 << s;
        for (int k = 0; k < 8; ++k) {
            const int ry  = refl(y + c_dy[k] * d);
            const int rx0 = refl(x0 + c_dx[k] * d);
            const int rx1 = refl(x1 + c_dx[k] * d);
            const float* crow = cb + ry * WW;
#pragma unroll
            for (int cin = 0; cin < 16; ++cin) {
                const float v0 = crow[cin * AREA + rx0];
                const float v1 = crow[cin * AREA + rx1];
                const float4* w4 = reinterpret_cast<const float4*>(&wf[(s * CSUR + k * 16 + cin) * 16]);
#pragma unroll
                for (int oq = 0; oq < 4; ++oq) {
                    const float4 w = w4[oq];
                    acc0[oq*4+0] = fmaf(w.x, v0, acc0[oq*4+0]); acc1[oq*4+0] = fmaf(w.x, v1, acc1[oq*4+0]);
                    acc0[oq*4+1] = fmaf(w.y, v0, acc0[oq*4+1]); acc1[oq*4+1] = fmaf(w.y, v1, acc1[oq*4+1]);
                    acc0[oq*4+2] = fmaf(w.z, v0, acc0[oq*4+2]); acc1[oq*4+2] = fmaf(w.z, v1, acc1[oq*4+2]);
                    acc0[oq*4+3] = fmaf(w.w, v0, acc0[oq*4+3]); acc1[oq*4+3] = fmaf(w.w, v1, acc1[oq*4+3]);
                }
            }
        }
    }
    {
        const float* crow = cb + y * WW;
#pragma unroll
        for (int cin = 0; cin < 16; ++cin) {
            const float v0 = crow[cin * AREA + x0];
            const float v1 = crow[cin * AREA + x1];
            const float4* w4 = reinterpret_cast<const float4*>(&wc[cin * 16]);
#pragma unroll
            for (int oq = 0; oq < 4; ++oq) {
                const float4 w = w4[oq];
                acc0[oq*4+0] = fmaf(-w.x, v0, acc0[oq*4+0]); acc1[oq*4+0] = fmaf(-w.x, v1, acc1[oq*4+0]);
                acc0[oq*4+1] = fmaf(-w.y, v0, acc0[oq*4+1]); acc1[oq*4+1] = fmaf(-w.y, v1, acc1[oq*4+1]);
                acc0[oq*4+2] = fmaf(-w.z, v0, acc0[oq*4+2]); acc1[oq*4+2] = fmaf(-w.z, v1, acc1[oq*4+2]);
                acc0[oq*4+3] = fmaf(-w.w, v0, acc0[oq*4+3]); acc1[oq*4+3] = fmaf(-w.w, v1, acc1[oq*4+3]);
            }
        }
    }
#pragma unroll
    for (int o = 0; o < 16; ++o) {
        const float scale = bn_gamma[o] * rsqrtf(bn_var[o] + 1e-5f);
        const float bias  = bn_beta[o] - bn_mean[o] * scale;
        const float r0 = fmaxf(acc0[o] + bias, 0.f);
        const float r1 = fmaxf(acc1[o] + bias, 0.f);
        out[((size_t)(b * 16 + o) * HH + y) * WW + x0] = r0;
        out[((size_t)(b * 16 + o) * HH + y) * WW + x1] = r1;
    }
}

// ---------------------------------------------------------------------------
extern "C" void kernel_launch(void* const* d_in, const int* in_sizes, int n_in,
                              void* d_out, int out_size, void* d_ws, size_t ws_size,
                              hipStream_t stream) {
    const float* cen      = (const float*)d_in[0];
    const float* q_w      = (const float*)d_in[1];
    const float* k_w      = (const float*)d_in[2];
    const float* v_w      = (const float*)d_in[3];
    const float* out_w    = (const float*)d_in[4];
    const float* bn_gamma = (const float*)d_in[5];
    const float* bn_beta  = (const float*)d_in[6];
    const float* bn_mean  = (const float*)d_in[7];
    const float* bn_var   = (const float*)d_in[8];
    float* out = (float*)d_out;

    char* ws = (char*)d_ws;
    const size_t PART_BYTES  = (size_t)8 * 16 * 20736 * 4;   // 10,616,832
    const size_t GFULL_BYTES = (size_t)16 * 20736 * 4;       //  1,327,104
    const size_t A_BYTES     = (size_t)16 * 64 * 128 * 4;    //    524,288
    const size_t NK_BYTES    = (size_t)16 * 128 * 4;         //      8,192
    const size_t NQ_BYTES    = (size_t)4 * 64 * 4;           //      1,024
    const size_t WEFF_BYTES  = (size_t)16 * 64 * 128 * 4;    //    524,288

    float* part  = (float*)(ws);
    float* Gfull = (float*)(ws + PART_BYTES);
    float* A     = (float*)(ws + PART_BYTES + GFULL_BYTES);
    float* normK = (float*)(ws + PART_BYTES + GFULL_BYTES + A_BYTES);
    float* normQ = (float*)(ws + PART_BYTES + GFULL_BYTES + A_BYTES + NK_BYTES);
    float* wEff  = (float*)(ws + PART_BYTES + GFULL_BYTES + A_BYTES + NK_BYTES + NQ_BYTES);
    float* wFin  = (float*)(ws + PART_BYTES + GFULL_BYTES + A_BYTES + NK_BYTES + NQ_BYTES + WEFF_BYTES);

    (void)hipMemsetAsync(part, 0, PART_BYTES, stream);
    (void)hipMemsetAsync(normK, 0, NK_BYTES, stream);
    k1_gram<<<dim3(64, 4, 4), 128, 0, stream>>>(cen, part);
    k1c<<<dim3(4, 4), 256, 0, stream>>>(part, q_w, Gfull, A, normQ);
    k2n<<<dim3(4, 16, 2), 256, 0, stream>>>(k_w, Gfull, normK);
    k2b<<<dim3(4, 4), 256, 0, stream>>>(k_w, v_w, A, normK, normQ, wEff);
    k2c<<<dim3(4, 4), 256, 0, stream>>>(out_w, bn_gamma, bn_var, wEff, wFin);
    k3_out<<<dim3(128, 4), 256, 0, stream>>>(cen, wFin, bn_gamma, bn_beta,
                                             bn_mean, bn_var, out);
}

// Round 9
// 418.140 us; speedup vs baseline: 1.0028x; 1.0028x over previous
//
#include <hip/hip_runtime.h>
#include <hip/hip_bf16.h>
#include <math.h>

#define HH 256
#define WW 256
#define AREA 65536
#define CIN 16
#define NS 4
#define CSUR 128
#define NEXT 144
#define NPAIR 45

typedef __attribute__((ext_vector_type(8))) short bf16x8;
typedef __attribute__((ext_vector_type(4))) float f32x4;

__constant__ int c_dy[8] = {-1,-1,-1, 0, 0, 1, 1, 1};
__constant__ int c_dx[8] = {-1, 0, 1,-1, 1,-1, 0, 1};

__device__ constexpr int CTI[NPAIR] = {
    0, 1,1, 2,2,2, 3,3,3,3, 4,4,4,4,4,
    5,5,5,5,5,5, 6,6,6,6,6,6,6, 7,7,7,7,7,7,7,7,
    8,8,8,8,8,8,8,8,8};
__device__ constexpr int CTJ[NPAIR] = {
    0, 0,1, 0,1,2, 0,1,2,3, 0,1,2,3,4,
    0,1,2,3,4,5, 0,1,2,3,4,5,6, 0,1,2,3,4,5,6,7,
    0,1,2,3,4,5,6,7,8};

__device__ __forceinline__ int refl(int v) {
    return v < 0 ? -v : (v > 255 ? 510 - v : v);
}

__device__ __forceinline__ unsigned pkbf(float a, float b) {
    __hip_bfloat162 h = __float22bfloat162_rn(make_float2(a, b));
    unsigned r;
    __builtin_memcpy(&r, &h, 4);
    return r;
}

// ---------------------------------------------------------------------------
// K1: diff Gram via compensated bf16 MFMA, 2 waves/block, K=32 tiles.
// LDS layout: per view tt (9), rows c (16): paired-row lines of 256B.
//   phys16(c,L) = (c>>1)*16 + (((L<<1)|(c&1)) ^ (((c>>1)&7)<<1)); uidx=phys16*4
//   L: 0..3 = hi px-chunks (8 px each), 4..7 = lo.
// grid (64 chunks x 4 rows, s=4, b=4), 128 threads. 8 partial buffers (chunk&7).
// ---------------------------------------------------------------------------
__global__ __launch_bounds__(128) void k1_gram(const float* __restrict__ cen,
                                               float* __restrict__ part) {
    const int chunk = blockIdx.x;
    const int s = blockIdx.y;
    const int b = blockIdx.z;
    const int d = 1 << s;
    const int t = threadIdx.x;
    const int lane = t & 63, wid = t >> 6;
    const int lr = lane & 15, lg = lane >> 4;
    const int cin = t >> 3, p0 = t & 7;
    const int y0 = chunk * 4;
    const float* base = cen + ((size_t)b * CIN + cin) * AREA;

    __shared__ unsigned lds[2][4608];   // 2 x 18,432 B

    // write offsets (uint idx within view block of 512 uints)
    const int cb16 = (cin >> 1) * 16, codd = cin & 1, cq = (cin >> 1) << 1;
#define PHI(L) (cb16 + ((((L) << 1) | codd) ^ cq))
    const int wHiA = PHI(p0 >> 2) * 4 + (p0 & 3);
    const int wLoA = PHI(4 + (p0 >> 2)) * 4 + (p0 & 3);
    const int wHiB = PHI(2 + (p0 >> 2)) * 4 + (p0 & 3);
    const int wLoB = PHI(6 + (p0 >> 2)) * 4 + (p0 & 3);
#undef PHI
    // read offsets (uint idx within view block)
    const int rb16 = (lr >> 1) * 16, rodd = lr & 1, rq = (lr >> 1) << 1;
    const int rHi = (rb16 + ((((lg) << 1) | rodd) ^ rq)) * 4;
    const int rLo = (rb16 + ((((4 + lg) << 1) | rodd) ^ rq)) * 4;

    const int xA0 = 2 * p0;

    auto stage = [&](unsigned* buf, int yy, int x0) {
        const float* rowy = base + yy * WW;
        const int xA = x0 + xA0, xB = xA + 16;
        const float2 cA = *(const float2*)(rowy + xA);
        const float2 cB = *(const float2*)(rowy + xB);
        {
            unsigned h = pkbf(cA.x, cA.y);
            buf[wHiA] = h;
            buf[wLoA] = pkbf(cA.x - __builtin_bit_cast(float, h << 16),
                             cA.y - __builtin_bit_cast(float, h & 0xFFFF0000u));
            h = pkbf(cB.x, cB.y);
            buf[wHiB] = h;
            buf[wLoB] = pkbf(cB.x - __builtin_bit_cast(float, h << 16),
                             cB.y - __builtin_bit_cast(float, h & 0xFFFF0000u));
        }
#pragma unroll
        for (int kk = 0; kk < 8; ++kk) {
            const int ys = refl(yy + c_dy[kk] * d);
            const float* rows = base + ys * WW;
            const int off = c_dx[kk] * d;
            float2 sA, sB;
            const int xa = xA + off;
            if (xa >= 0 && xa <= 254) sA = *(const float2*)(rows + xa);
            else { sA.x = rows[refl(xa)]; sA.y = rows[refl(xa + 1)]; }
            const int xb2 = xB + off;
            if (xb2 >= 0 && xb2 <= 254) sB = *(const float2*)(rows + xb2);
            else { sB.x = rows[refl(xb2)]; sB.y = rows[refl(xb2 + 1)]; }
            unsigned* vb = buf + (kk + 1) * 512;
            float da = sA.x - cA.x, db = sA.y - cA.y;
            unsigned h = pkbf(da, db);
            vb[wHiA] = h;
            vb[wLoA] = pkbf(da - __builtin_bit_cast(float, h << 16),
                            db - __builtin_bit_cast(float, h & 0xFFFF0000u));
            da = sB.x - cB.x; db = sB.y - cB.y;
            h = pkbf(da, db);
            vb[wHiB] = h;
            vb[wLoB] = pkbf(da - __builtin_bit_cast(float, h << 16),
                            db - __builtin_bit_cast(float, h & 0xFFFF0000u));
        }
    };

    f32x4 acc[23];
#pragma unroll
    for (int i = 0; i < 23; ++i) acc[i] = (f32x4){0.f, 0.f, 0.f, 0.f};

    stage(lds[0], y0, 0);
    __syncthreads();

    for (int ph = 0; ph < 32; ++ph) {
        const int cur = ph & 1;
        if (ph + 1 < 32) {
            stage(lds[cur ^ 1], y0 + ((ph + 1) >> 3), ((ph + 1) & 7) * 32);
        }
        const unsigned* m = lds[cur];
        bf16x8 fh[9], fl[9];
#pragma unroll
        for (int tt = 0; tt < 9; ++tt) {
            fh[tt] = *(const bf16x8*)(m + tt * 512 + rHi);
            fl[tt] = *(const bf16x8*)(m + tt * 512 + rLo);
        }
        if (wid == 0) {
#pragma unroll
            for (int p = 0; p < 23; ++p) {
                const int i = CTI[p], j = CTJ[p];
                acc[p] = __builtin_amdgcn_mfma_f32_16x16x32_bf16(fh[i], fh[j], acc[p], 0, 0, 0);
                acc[p] = __builtin_amdgcn_mfma_f32_16x16x32_bf16(fh[i], fl[j], acc[p], 0, 0, 0);
                acc[p] = __builtin_amdgcn_mfma_f32_16x16x32_bf16(fl[i], fh[j], acc[p], 0, 0, 0);
            }
        } else {
#pragma unroll
            for (int p = 0; p < 22; ++p) {
                const int i = CTI[23 + p], j = CTJ[23 + p];
                acc[p] = __builtin_amdgcn_mfma_f32_16x16x32_bf16(fh[i], fh[j], acc[p], 0, 0, 0);
                acc[p] = __builtin_amdgcn_mfma_f32_16x16x32_bf16(fh[i], fl[j], acc[p], 0, 0, 0);
                acc[p] = __builtin_amdgcn_mfma_f32_16x16x32_bf16(fl[i], fh[j], acc[p], 0, 0, 0);
            }
        }
        __syncthreads();
    }

    float* tb = part + (size_t)((chunk & 7) * 16 + b * 4 + s) * 20736;
    const int np = (wid == 0) ? 23 : 22;
    const int pb = (wid == 0) ? 0 : 23;
#pragma unroll
    for (int p = 0; p < 23; ++p) {
        if (p < np) {
            const int gi0 = CTI[pb + p] * 16 + lg * 4;
            const int gj  = CTJ[pb + p] * 16 + lr;
            const f32x4 a = acc[p];
#pragma unroll
            for (int r = 0; r < 4; ++r)
                atomicAdd(&tb[(gi0 + r) * 144 + gj], a[r]);
        }
    }
}

// ---------------------------------------------------------------------------
// K1c: sum 8 partials + mirror -> Gfull ; A = q_w·G ; normQ. grid (4,4).
// ---------------------------------------------------------------------------
__global__ __launch_bounds__(256) void k1c(const float* __restrict__ part,
                                           const float* __restrict__ q_w,
                                           float* __restrict__ Gfull,
                                           float* __restrict__ A,
                                           float* __restrict__ normQ) {
    const int s = blockIdx.x, b = blockIdx.y, bs = b * 4 + s;
    const int t = threadIdx.x;
    __shared__ float Ts[144][148];
    for (int e = t; e < 20736; e += 256) {
        const int i = e / 144, j = e - i * 144;
        if (i >= j) {
            float v = 0.f;
#pragma unroll
            for (int c = 0; c < 8; ++c)
                v += part[(size_t)(c * 16 + bs) * 20736 + e];
            Ts[i][j] = v;
            Ts[j][i] = v;
        }
    }
    __syncthreads();
    float* go = Gfull + (size_t)bs * 20736;
    for (int e = t; e < 20736; e += 256) {
        const int i = e / 144, j = e - i * 144;
        go[e] = Ts[i][j];
    }
    for (int e = t; e < 8192; e += 256) {
        const int jq = e >> 7, cp = e & 127;
        const float* qrow = q_w + jq * 16;
        const float* trow = &Ts[16 + cp][0];
        float a = 0.f;
#pragma unroll
        for (int cin = 0; cin < 16; ++cin) a = fmaf(qrow[cin], trow[cin], a);
        A[((size_t)bs * 64 + jq) * 128 + cp] = a;
    }
    if (s == 0 && t < 64) {
        float nq = 0.f;
#pragma unroll
        for (int c1 = 0; c1 < 16; ++c1) {
            float ra = 0.f;
#pragma unroll
            for (int c2 = 0; c2 < 16; ++c2)
                ra = fmaf(q_w[t * 16 + c2], Ts[c1][c2], ra);
            nq = fmaf(q_w[t * 16 + c1], ra, nq);
        }
        normQ[b * 64 + t] = nq;
    }
}

// ---------------------------------------------------------------------------
// K2n: normK[bs][ck] = k_row·H·k_rowT, split (32 ck) x (64 i) per block.
// grid (ckg=4, bs=16, ih=2), 256 threads.
// ---------------------------------------------------------------------------
__global__ __launch_bounds__(256) void k2n(const float* __restrict__ k_w,
                                           const float* __restrict__ Gfull,
                                           float* __restrict__ normK) {
    const int ckg = blockIdx.x, bs = blockIdx.y, ih = blockIdx.z;
    const int s = bs & 3;
    const int t = threadIdx.x;
    __shared__ float kS[32][129];
    __shared__ float Hs[64][129];
    __shared__ float red[256];
    for (int e = t; e < 4096; e += 256) {
        const int r = e >> 7, j = e & 127;
        kS[r][j] = k_w[(size_t)(s * 128 + ckg * 32 + r) * 128 + j];
    }
    for (int e = t; e < 8192; e += 256) {
        const int r = e >> 7, j = e & 127;
        Hs[r][j] = Gfull[(size_t)bs * 20736 + (16 + ih * 64 + r) * 144 + 16 + j];
    }
    __syncthreads();
    const int ckl = t & 31, p = t >> 5;
    float m[8];
#pragma unroll
    for (int i = 0; i < 8; ++i) m[i] = 0.f;
    for (int j = 0; j < 128; ++j) {
        const float kv = kS[ckl][j];
#pragma unroll
        for (int i = 0; i < 8; ++i) m[i] = fmaf(Hs[p * 8 + i][j], kv, m[i]);
    }
    float prt = 0.f;
#pragma unroll
    for (int i = 0; i < 8; ++i)
        prt = fmaf(kS[ckl][ih * 64 + p * 8 + i], m[i], prt);
    red[t] = prt;
    __syncthreads();
    if (t < 32) {
        float s8 = 0.f;
#pragma unroll
        for (int q = 0; q < 8; ++q) s8 += red[q * 32 + t];
        atomicAdd(&normK[(size_t)bs * 128 + ckg * 32 + t], s8);
    }
}

// ---------------------------------------------------------------------------
// K2b: scores -> instance norm -> softmax -> wEff. grid (a=4, b=4), 256 thr.
// ---------------------------------------------------------------------------
__global__ __launch_bounds__(256) void k2b(const float* __restrict__ k_w,
                                           const float* __restrict__ v_w,
                                           const float* __restrict__ A,
                                           const float* __restrict__ normK,
                                           const float* __restrict__ normQ,
                                           float* __restrict__ wEff) {
    const int a = blockIdx.x, b = blockIdx.y;
    const int t = threadIdx.x;
    __shared__ float AS[4][16][128];
    __shared__ float kv[4][32][132];
    __shared__ float sc[2048];
    __shared__ float red[256];
    __shared__ float rowred[256];
    __shared__ float rowmax[16], rowsum[16];
    __shared__ float s_mu, s_rs;

    for (int idx = t; idx < 8192; idx += 256) {
        const int sk = idx >> 11, rr = (idx >> 7) & 15, cp = idx & 127;
        const int jq = (rr & 3) * 16 + 4 * a + (rr >> 2);
        AS[sk][rr][cp] = A[((size_t)(b * 4 + sk) * 64 + jq) * 128 + cp];
    }
    for (int idx = t; idx < 16384; idx += 256) {
        const int sk = idx >> 12, ckl = (idx >> 7) & 31, cp = idx & 127;
        kv[sk][ckl][cp] = k_w[((size_t)sk * 128 + 32 * a + ckl) * 128 + cp];
    }
    __syncthreads();
    for (int e = t; e < 2048; e += 256) {
        const int r = e >> 7, dd = e & 127;
        const int sk = dd & 3, ckl = dd >> 2;
        const float4* Ar = (const float4*)(&AS[sk][r][0]);
        const float4* kr = (const float4*)(&kv[sk][ckl][0]);
        float4 pv = {0.f, 0.f, 0.f, 0.f};
#pragma unroll 8
        for (int jj = 0; jj < 32; ++jj) {
            const float4 h = Ar[jj], k4 = kr[jj];
            pv.x = fmaf(h.x, k4.x, pv.x);
            pv.y = fmaf(h.y, k4.y, pv.y);
            pv.z = fmaf(h.z, k4.z, pv.z);
            pv.w = fmaf(h.w, k4.w, pv.w);
        }
        const float dot = pv.x + pv.y + pv.z + pv.w;
        const int jq = (r & 3) * 16 + 4 * a + (r >> 2);
        const float qn = fmaxf(sqrtf(fmaxf(normQ[b * 64 + jq], 0.f)), 1e-12f);
        const float kn = fmaxf(sqrtf(fmaxf(normK[(size_t)(b * 4 + sk) * 128 + 32 * a + ckl], 0.f)), 1e-12f);
        sc[e] = dot / (qn * kn * 256.0f);
    }
    __syncthreads();
    for (int idx = t; idx < 16384; idx += 256) {
        const int sk = idx >> 12, m = (idx >> 7) & 31, cp = idx & 127;
        kv[sk][m][cp] = v_w[((size_t)sk * 128 + 32 * a + m) * 128 + cp];
    }
    {
        float p = 0.f;
        for (int e = t; e < 2048; e += 256) p += sc[e];
        red[t] = p; __syncthreads();
        for (int off = 128; off > 0; off >>= 1) {
            if (t < off) red[t] += red[t + off];
            __syncthreads();
        }
        if (t == 0) s_mu = red[0] * (1.f / 2048.f);
        __syncthreads();
    }
    {
        const float mu = s_mu;
        float p = 0.f;
        for (int e = t; e < 2048; e += 256) { const float z = sc[e] - mu; p += z * z; }
        red[t] = p; __syncthreads();
        for (int off = 128; off > 0; off >>= 1) {
            if (t < off) red[t] += red[t + off];
            __syncthreads();
        }
        if (t == 0) s_rs = rsqrtf(red[0] * (1.f / 2048.f) + 1e-5f);
        __syncthreads();
    }
    const float mu = s_mu, rs = s_rs;
    const int r = t >> 4, l = t & 15;
    {
        float m = -1e30f;
#pragma unroll
        for (int j = 0; j < 8; ++j) {
            const float z = (sc[r * 128 + l + j * 16] - mu) * rs;
            m = fmaxf(m, z);
        }
        rowred[t] = m; __syncthreads();
        if (l == 0) {
            float m2 = rowred[r * 16];
            for (int j = 1; j < 16; ++j) m2 = fmaxf(m2, rowred[r * 16 + j]);
            rowmax[r] = m2;
        }
        __syncthreads();
    }
    {
        float p = 0.f;
#pragma unroll
        for (int j = 0; j < 8; ++j) {
            const float z = (sc[r * 128 + l + j * 16] - mu) * rs;
            p += expf(z - rowmax[r]);
        }
        rowred[t] = p; __syncthreads();
        if (l == 0) {
            float p2 = 0.f;
            for (int j = 0; j < 16; ++j) p2 += rowred[r * 16 + j];
            rowsum[r] = p2;
        }
        __syncthreads();
    }
    {
        float vals[8];
#pragma unroll
        for (int j = 0; j < 8; ++j) {
            const float z = (sc[r * 128 + l + j * 16] - mu) * rs;
            vals[j] = expf(z - rowmax[r]) / rowsum[r];
        }
        __syncthreads();
#pragma unroll
        for (int j = 0; j < 8; ++j) sc[r * 128 + l + j * 16] = vals[j];
        __syncthreads();
    }
    for (int e = t; e < 8192; e += 256) {
        const int sk = e >> 11, r2 = (e >> 7) & 15, cp = e & 127;
        float w = 0.f;
#pragma unroll
        for (int m = 0; m < 32; ++m)
            w = fmaf(sc[r2 * 128 + 4 * m + sk], kv[sk][m][cp], w);
        wEff[((size_t)(b * 4 + sk) * 64 + (a * 16 + r2)) * 128 + cp] = w;
    }
}

// ---------------------------------------------------------------------------
// K2c: wFinal. grid (s=4, b=4), 256 threads.
// ---------------------------------------------------------------------------
__global__ __launch_bounds__(256) void k2c(const float* __restrict__ out_w,
                                           const float* __restrict__ bn_gamma,
                                           const float* __restrict__ bn_var,
                                           const float* __restrict__ wEff,
                                           float* __restrict__ wFinal) {
    const int s = blockIdx.x, b = blockIdx.y;
    const int t = threadIdx.x;
    __shared__ float we[64][128];
    for (int idx = t; idx < 8192; idx += 256) {
        const int j = idx >> 7, cp = idx & 127;
        we[j][cp] = wEff[((size_t)(b * 4 + s) * 64 + j) * 128 + cp];
    }
    __syncthreads();
    for (int e = t; e < 2048; e += 256) {
        const int o = e >> 7, cp = e & 127;
        float w = 0.f;
#pragma unroll 16
        for (int j = 0; j < 64; ++j)
            w = fmaf(out_w[o * 64 + j], we[j][cp], w);
        const float scale = bn_gamma[o] * rsqrtf(bn_var[o] + 1e-5f);
        wFinal[((size_t)(b * 4 + s) * 16 + o) * 128 + cp] = w * scale;
    }
}

// ---------------------------------------------------------------------------
// K3: out = relu( sum_s wFinal_s·sur_s + bias ). grid (128, b=4), 256 thr.
// ---------------------------------------------------------------------------
__global__ __launch_bounds__(256) void k3_out(const float* __restrict__ cen,
                                              const float* __restrict__ wFinal,
                                              const float* __restrict__ bn_gamma,
                                              const float* __restrict__ bn_beta,
                                              const float* __restrict__ bn_mean,
                                              const float* __restrict__ bn_var,
                                              float* __restrict__ out) {
    const int by = blockIdx.x;
    const int b  = blockIdx.y;
    const int t  = threadIdx.x;
    __shared__ __align__(16) float wf[NS * CSUR * 16];
    __shared__ __align__(16) float wc[16 * 16];

    for (int e = t; e < NS * CSUR * 16; e += 256) {
        const int s = e >> 11, cp = (e >> 4) & 127, o = e & 15;
        wf[e] = wFinal[((size_t)(b * NS + s) * 16 + o) * CSUR + cp];
    }
    __syncthreads();
    {
        const int cin = t >> 4, o = t & 15;
        float sum = 0.f;
#pragma unroll
        for (int s = 0; s < NS; ++s)
#pragma unroll
            for (int k = 0; k < 8; ++k)
                sum += wf[(s * CSUR + k * 16 + cin) * 16 + o];
        wc[cin * 16 + o] = sum;
    }
    __syncthreads();

    const int x0 = t & 127;
    const int x1 = x0 + 128;
    const int y  = by * 2 + (t >> 7);
    const float* cb = cen + (size_t)b * CIN * AREA;

    float acc0[16], acc1[16];
#pragma unroll
    for (int o = 0; o < 16; ++o) { acc0[o] = 0.f; acc1[o] = 0.f; }

    for (int s = 0; s < NS; ++s) {
        const int d = 1 << s;
        for (int k = 0; k < 8; ++k) {
            const int ry  = refl(y + c_dy[k] * d);
            const int rx0 = refl(x0 + c_dx[k] * d);
            const int rx1 = refl(x1 + c_dx[k] * d);
            const float* crow = cb + ry * WW;
#pragma unroll
            for (int cin = 0; cin < 16; ++cin) {
                const float v0 = crow[cin * AREA + rx0];
                const float v1 = crow[cin * AREA + rx1];
                const float4* w4 = reinterpret_cast<const float4*>(&wf[(s * CSUR + k * 16 + cin) * 16]);
#pragma unroll
                for (int oq = 0; oq < 4; ++oq) {
                    const float4 w = w4[oq];
                    acc0[oq*4+0] = fmaf(w.x, v0, acc0[oq*4+0]); acc1[oq*4+0] = fmaf(w.x, v1, acc1[oq*4+0]);
                    acc0[oq*4+1] = fmaf(w.y, v0, acc0[oq*4+1]); acc1[oq*4+1] = fmaf(w.y, v1, acc1[oq*4+1]);
                    acc0[oq*4+2] = fmaf(w.z, v0, acc0[oq*4+2]); acc1[oq*4+2] = fmaf(w.z, v1, acc1[oq*4+2]);
                    acc0[oq*4+3] = fmaf(w.w, v0, acc0[oq*4+3]); acc1[oq*4+3] = fmaf(w.w, v1, acc1[oq*4+3]);
                }
            }
        }
    }
    {
        const float* crow = cb + y * WW;
#pragma unroll
        for (int cin = 0; cin < 16; ++cin) {
            const float v0 = crow[cin * AREA + x0];
            const float v1 = crow[cin * AREA + x1];
            const float4* w4 = reinterpret_cast<const float4*>(&wc[cin * 16]);
#pragma unroll
            for (int oq = 0; oq < 4; ++oq) {
                const float4 w = w4[oq];
                acc0[oq*4+0] = fmaf(-w.x, v0, acc0[oq*4+0]); acc1[oq*4+0] = fmaf(-w.x, v1, acc1[oq*4+0]);
                acc0[oq*4+1] = fmaf(-w.y, v0, acc0[oq*4+1]); acc1[oq*4+1] = fmaf(-w.y, v1, acc1[oq*4+1]);
                acc0[oq*4+2] = fmaf(-w.z, v0, acc0[oq*4+2]); acc1[oq*4+2] = fmaf(-w.z, v1, acc1[oq*4+2]);
                acc0[oq*4+3] = fmaf(-w.w, v0, acc0[oq*4+3]); acc1[oq*4+3] = fmaf(-w.w, v1, acc1[oq*4+3]);
            }
        }
    }
#pragma unroll
    for (int o = 0; o < 16; ++o) {
        const float scale = bn_gamma[o] * rsqrtf(bn_var[o] + 1e-5f);
        const float bias  = bn_beta[o] - bn_mean[o] * scale;
        const float r0 = fmaxf(acc0[o] + bias, 0.f);
        const float r1 = fmaxf(acc1[o] + bias, 0.f);
        out[((size_t)(b * 16 + o) * HH + y) * WW + x0] = r0;
        out[((size_t)(b * 16 + o) * HH + y) * WW + x1] = r1;
    }
}

// ---------------------------------------------------------------------------
extern "C" void kernel_launch(void* const* d_in, const int* in_sizes, int n_in,
                              void* d_out, int out_size, void* d_ws, size_t ws_size,
                              hipStream_t stream) {
    const float* cen      = (const float*)d_in[0];
    const float* q_w      = (const float*)d_in[1];
    const float* k_w      = (const float*)d_in[2];
    const float* v_w      = (const float*)d_in[3];
    const float* out_w    = (const float*)d_in[4];
    const float* bn_gamma = (const float*)d_in[5];
    const float* bn_beta  = (const float*)d_in[6];
    const float* bn_mean  = (const float*)d_in[7];
    const float* bn_var   = (const float*)d_in[8];
    float* out = (float*)d_out;

    char* ws = (char*)d_ws;
    const size_t PART_BYTES  = (size_t)8 * 16 * 20736 * 4;   // 10,616,832
    const size_t GFULL_BYTES = (size_t)16 * 20736 * 4;       //  1,327,104
    const size_t A_BYTES     = (size_t)16 * 64 * 128 * 4;    //    524,288
    const size_t NK_BYTES    = (size_t)16 * 128 * 4;         //      8,192
    const size_t NQ_BYTES    = (size_t)4 * 64 * 4;           //      1,024
    const size_t WEFF_BYTES  = (size_t)16 * 64 * 128 * 4;    //    524,288

    float* part  = (float*)(ws);
    float* Gfull = (float*)(ws + PART_BYTES);
    float* A     = (float*)(ws + PART_BYTES + GFULL_BYTES);
    float* normK = (float*)(ws + PART_BYTES + GFULL_BYTES + A_BYTES);
    float* normQ = (float*)(ws + PART_BYTES + GFULL_BYTES + A_BYTES + NK_BYTES);
    float* wEff  = (float*)(ws + PART_BYTES + GFULL_BYTES + A_BYTES + NK_BYTES + NQ_BYTES);
    float* wFin  = (float*)(ws + PART_BYTES + GFULL_BYTES + A_BYTES + NK_BYTES + NQ_BYTES + WEFF_BYTES);

    (void)hipMemsetAsync(part, 0, PART_BYTES, stream);
    (void)hipMemsetAsync(normK, 0, NK_BYTES, stream);
    k1_gram<<<dim3(64, 4, 4), 128, 0, stream>>>(cen, part);
    k1c<<<dim3(4, 4), 256, 0, stream>>>(part, q_w, Gfull, A, normQ);
    k2n<<<dim3(4, 16, 2), 256, 0, stream>>>(k_w, Gfull, normK);
    k2b<<<dim3(4, 4), 256, 0, stream>>>(k_w, v_w, A, normK, normQ, wEff);
    k2c<<<dim3(4, 4), 256, 0, stream>>>(out_w, bn_gamma, bn_var, wEff, wFin);
    k3_out<<<dim3(128, 4), 256, 0, stream>>>(cen, wFin, bn_gamma, bn_beta,
                                             bn_mean, bn_var, out);
}

// Round 10
// 311.952 us; speedup vs baseline: 1.3441x; 1.3404x over previous
//
#include <hip/hip_runtime.h>
#include <hip/hip_bf16.h>
#include <math.h>

#define HH 256
#define WW 256
#define AREA 65536
#define CIN 16
#define NS 4
#define CSUR 128
#define NEXT 144
#define NPAIR 45

typedef __attribute__((ext_vector_type(8))) short bf16x8;
typedef __attribute__((ext_vector_type(4))) float f32x4;

__constant__ int c_dy[8] = {-1,-1,-1, 0, 0, 1, 1, 1};
__constant__ int c_dx[8] = {-1, 0, 1,-1, 1,-1, 0, 1};

__device__ constexpr int CTI[NPAIR] = {
    0, 1,1, 2,2,2, 3,3,3,3, 4,4,4,4,4,
    5,5,5,5,5,5, 6,6,6,6,6,6,6, 7,7,7,7,7,7,7,7,
    8,8,8,8,8,8,8,8,8};
__device__ constexpr int CTJ[NPAIR] = {
    0, 0,1, 0,1,2, 0,1,2,3, 0,1,2,3,4,
    0,1,2,3,4,5, 0,1,2,3,4,5,6, 0,1,2,3,4,5,6,7,
    0,1,2,3,4,5,6,7,8};

__device__ __forceinline__ int refl(int v) {
    return v < 0 ? -v : (v > 255 ? 510 - v : v);
}

// pack 2 floats to bf16x2 via HW cvt_pk (RNE)
__device__ __forceinline__ unsigned pkbf(float a, float b) {
    __hip_bfloat162 h = __float22bfloat162_rn(make_float2(a, b));
    unsigned r;
    __builtin_memcpy(&r, &h, 4);
    return r;
}

// write hi+lo pair into swizzled row: row c = 32 uints [hi g0..3 | lo g4..7],
// group g stored at physical slot g ^ (c&7).
__device__ __forceinline__ void wp(unsigned* __restrict__ m,
                                   int c, int pxp, float a, float b) {
    const int base = c * 32, sw = c & 7, gi = pxp >> 2, e = pxp & 3;
    const unsigned h = pkbf(a, b);
    m[base + ((gi ^ sw) << 2) + e] = h;
    const float fa = __builtin_bit_cast(float, h << 16);
    const float fb = __builtin_bit_cast(float, h & 0xFFFF0000u);
    m[base + (((4 + gi) ^ sw) << 2) + e] = pkbf(a - fa, b - fb);
}

// stage one kstep (32 pixels: row y, cols x0..x0+31)
__device__ __forceinline__ void stage_tile(unsigned* __restrict__ m,
                                           const float* __restrict__ base,
                                           int y, int x0, int cin, int pxp, int d) {
    constexpr int DY[8] = {-1,-1,-1, 0, 0, 1, 1, 1};
    constexpr int DX[8] = {-1, 0, 1,-1, 1,-1, 0, 1};
    const int x = x0 + 2 * pxp;
    const float2 cv = *(const float2*)(base + y * WW + x);
    wp(m, cin, pxp, cv.x, cv.y);                  // center rows 0..15
#pragma unroll
    for (int kk = 0; kk < 8; ++kk) {
        const int ys  = refl(y + DY[kk] * d);
        const int xs0 = refl(x + DX[kk] * d);
        const int xs1 = refl(x + 1 + DX[kk] * d);
        const float* row = base + ys * WW;
        wp(m, 16 + kk * 16 + cin, pxp, row[xs0] - cv.x, row[xs1] - cv.y);
    }
}

// ---------------------------------------------------------------------------
// K1 (r6-proven): diff Gram via compensated bf16 MFMA, 4 waves, K=32 tiles.
// grid (64 chunks x 4 rows, s=4, b=4), 256 threads. 4 partial buffers (chunk&3).
// ---------------------------------------------------------------------------
__global__ __launch_bounds__(256) void k1_gram(const float* __restrict__ cen,
                                               float* __restrict__ part) {
    const int chunk = blockIdx.x;          // 0..63 -> 4 rows each
    const int s = blockIdx.y;
    const int b = blockIdx.z;
    const int d = 1 << s;
    const int t = threadIdx.x;
    const int lane = t & 63, wid = t >> 6;
    const int lr = lane & 15, lg = lane >> 4;
    const int cin = t >> 4, pxp = t & 15;
    const int y0 = chunk * 4;
    const float* base = cen + ((size_t)b * CIN + cin) * AREA;

    __shared__ unsigned lds[2][NEXT * 32];

    const int ghi = ((lg ^ (lr & 7)) << 2);
    const int glo = (((4 + lg) ^ (lr & 7)) << 2);

    f32x4 acc[12];
#pragma unroll
    for (int i = 0; i < 12; ++i) acc[i] = (f32x4){0.f, 0.f, 0.f, 0.f};

    stage_tile(lds[0], base, y0, 0, cin, pxp, d);
    __syncthreads();

    for (int st = 0; st < 32; ++st) {
        const int cur = st & 1;
        if (st + 1 < 32) {
            stage_tile(lds[cur ^ 1], base, y0 + ((st + 1) >> 3),
                       ((st + 1) & 7) * 32, cin, pxp, d);
        }
        const unsigned* m = lds[cur];
        bf16x8 fh[9], fl[9];
#pragma unroll
        for (int tt = 0; tt < 9; ++tt) {
            const int rb = (tt * 16 + lr) * 32;
            fh[tt] = *(const bf16x8*)(m + rb + ghi);
            fl[tt] = *(const bf16x8*)(m + rb + glo);
        }
#pragma unroll
        for (int p = 0; p < NPAIR; ++p) {
            if ((p & 3) == wid) {
                const int i = CTI[p], j = CTJ[p], a = p >> 2;
                acc[a] = __builtin_amdgcn_mfma_f32_16x16x32_bf16(fh[i], fh[j], acc[a], 0, 0, 0);
                acc[a] = __builtin_amdgcn_mfma_f32_16x16x32_bf16(fh[i], fl[j], acc[a], 0, 0, 0);
                acc[a] = __builtin_amdgcn_mfma_f32_16x16x32_bf16(fl[i], fh[j], acc[a], 0, 0, 0);
            }
        }
        __syncthreads();
    }

    float* tb = part + (size_t)((chunk & 3) * 16 + b * 4 + s) * 20736;
#pragma unroll
    for (int p = 0; p < NPAIR; ++p) {
        if ((p & 3) == wid) {
            const int gi0 = CTI[p] * 16 + lg * 4;
            const int gj  = CTJ[p] * 16 + lr;
            const f32x4 a = acc[p >> 2];
#pragma unroll
            for (int r = 0; r < 4; ++r)
                atomicAdd(&tb[(gi0 + r) * 144 + gj], a[r]);
        }
    }
}

// ---------------------------------------------------------------------------
// K1c: per 16-row stripe: sum 4 partials + mirror -> Gfull rows; A-slice;
// normQ (z==0,s==0). grid (s=4, b=4, z=9), 256 threads.
// ---------------------------------------------------------------------------
__global__ __launch_bounds__(256) void k1c(const float* __restrict__ part,
                                           const float* __restrict__ q_w,
                                           float* __restrict__ Gfull,
                                           float* __restrict__ A,
                                           float* __restrict__ normQ) {
    const int s = blockIdx.x, b = blockIdx.y, z = blockIdx.z, bs = b * 4 + s;
    const int t = threadIdx.x;
    const int i0 = z * 16;
    __shared__ float Ts[16][148];
    const float* p0 = part + (size_t)(0 * 16 + bs) * 20736;
    const float* p1 = part + (size_t)(1 * 16 + bs) * 20736;
    const float* p2 = part + (size_t)(2 * 16 + bs) * 20736;
    const float* p3 = part + (size_t)(3 * 16 + bs) * 20736;
    for (int e = t; e < 16 * 144; e += 256) {
        const int il = e / 144, j = e - il * 144;
        const int i = i0 + il;
        const int src = (i >= j) ? (i * 144 + j) : (j * 144 + i);
        Ts[il][j] = p0[src] + p1[src] + p2[src] + p3[src];
    }
    __syncthreads();
    float* go = Gfull + (size_t)bs * 20736 + (size_t)i0 * 144;
    for (int e = t; e < 16 * 144; e += 256) {
        const int il = e / 144, j = e - il * 144;
        go[e] = Ts[il][j];
    }
    if (z >= 1) {
        for (int e = t; e < 1024; e += 256) {
            const int il = e >> 6, jq = e & 63;
            const float* qr = q_w + jq * 16;
            float aa = 0.f;
#pragma unroll
            for (int c = 0; c < 16; ++c) aa = fmaf(qr[c], Ts[il][c], aa);
            A[((size_t)bs * 64 + jq) * 128 + (i0 - 16 + il)] = aa;
        }
    }
    if (z == 0 && s == 0 && t < 64) {
        float nq = 0.f;
#pragma unroll
        for (int c1 = 0; c1 < 16; ++c1) {
            float ra = 0.f;
#pragma unroll
            for (int c2 = 0; c2 < 16; ++c2)
                ra = fmaf(q_w[t * 16 + c2], Ts[c1][c2], ra);
            nq = fmaf(q_w[t * 16 + c1], ra, nq);
        }
        normQ[b * 64 + t] = nq;
    }
}

// ---------------------------------------------------------------------------
// K2n: normK[bs][ck] = k_row·H·k_rowT, split (32 ck) x (64 i) per block.
// grid (ckg=4, bs=16, ih=2), 256 threads.
// ---------------------------------------------------------------------------
__global__ __launch_bounds__(256) void k2n(const float* __restrict__ k_w,
                                           const float* __restrict__ Gfull,
                                           float* __restrict__ normK) {
    const int ckg = blockIdx.x, bs = blockIdx.y, ih = blockIdx.z;
    const int s = bs & 3;
    const int t = threadIdx.x;
    __shared__ float kS[32][129];
    __shared__ float Hs[64][129];
    __shared__ float red[256];
    for (int e = t; e < 4096; e += 256) {
        const int r = e >> 7, j = e & 127;
        kS[r][j] = k_w[(size_t)(s * 128 + ckg * 32 + r) * 128 + j];
    }
    for (int e = t; e < 8192; e += 256) {
        const int r = e >> 7, j = e & 127;
        Hs[r][j] = Gfull[(size_t)bs * 20736 + (16 + ih * 64 + r) * 144 + 16 + j];
    }
    __syncthreads();
    const int ckl = t & 31, p = t >> 5;
    float m[8];
#pragma unroll
    for (int i = 0; i < 8; ++i) m[i] = 0.f;
    for (int j = 0; j < 128; ++j) {
        const float kv = kS[ckl][j];
#pragma unroll
        for (int i = 0; i < 8; ++i) m[i] = fmaf(Hs[p * 8 + i][j], kv, m[i]);
    }
    float prt = 0.f;
#pragma unroll
    for (int i = 0; i < 8; ++i)
        prt = fmaf(kS[ckl][ih * 64 + p * 8 + i], m[i], prt);
    red[t] = prt;
    __syncthreads();
    if (t < 32) {
        float s8 = 0.f;
#pragma unroll
        for (int q = 0; q < 8; ++q) s8 += red[q * 32 + t];
        atomicAdd(&normK[(size_t)bs * 128 + ckg * 32 + t], s8);
    }
}

// ---------------------------------------------------------------------------
// K2b: scores -> instance norm -> softmax -> wEff. grid (a=4, b=4), 256 thr.
// ---------------------------------------------------------------------------
__global__ __launch_bounds__(256) void k2b(const float* __restrict__ k_w,
                                           const float* __restrict__ v_w,
                                           const float* __restrict__ A,
                                           const float* __restrict__ normK,
                                           const float* __restrict__ normQ,
                                           float* __restrict__ wEff) {
    const int a = blockIdx.x, b = blockIdx.y;
    const int t = threadIdx.x;
    __shared__ float AS[4][16][128];
    __shared__ float kv[4][32][132];
    __shared__ float sc[2048];
    __shared__ float red[256];
    __shared__ float rowred[256];
    __shared__ float rowmax[16], rowsum[16];
    __shared__ float s_mu, s_rs;

    for (int idx = t; idx < 8192; idx += 256) {
        const int sk = idx >> 11, rr = (idx >> 7) & 15, cp = idx & 127;
        const int jq = (rr & 3) * 16 + 4 * a + (rr >> 2);
        AS[sk][rr][cp] = A[((size_t)(b * 4 + sk) * 64 + jq) * 128 + cp];
    }
    for (int idx = t; idx < 16384; idx += 256) {
        const int sk = idx >> 12, ckl = (idx >> 7) & 31, cp = idx & 127;
        kv[sk][ckl][cp] = k_w[((size_t)sk * 128 + 32 * a + ckl) * 128 + cp];
    }
    __syncthreads();
    for (int e = t; e < 2048; e += 256) {
        const int r = e >> 7, dd = e & 127;
        const int sk = dd & 3, ckl = dd >> 2;
        const float4* Ar = (const float4*)(&AS[sk][r][0]);
        const float4* kr = (const float4*)(&kv[sk][ckl][0]);
        float4 pv = {0.f, 0.f, 0.f, 0.f};
#pragma unroll 8
        for (int jj = 0; jj < 32; ++jj) {
            const float4 h = Ar[jj], k4 = kr[jj];
            pv.x = fmaf(h.x, k4.x, pv.x);
            pv.y = fmaf(h.y, k4.y, pv.y);
            pv.z = fmaf(h.z, k4.z, pv.z);
            pv.w = fmaf(h.w, k4.w, pv.w);
        }
        const float dot = pv.x + pv.y + pv.z + pv.w;
        const int jq = (r & 3) * 16 + 4 * a + (r >> 2);
        const float qn = fmaxf(sqrtf(fmaxf(normQ[b * 64 + jq], 0.f)), 1e-12f);
        const float kn = fmaxf(sqrtf(fmaxf(normK[(size_t)(b * 4 + sk) * 128 + 32 * a + ckl], 0.f)), 1e-12f);
        sc[e] = dot / (qn * kn * 256.0f);
    }
    __syncthreads();
    for (int idx = t; idx < 16384; idx += 256) {
        const int sk = idx >> 12, m = (idx >> 7) & 31, cp = idx & 127;
        kv[sk][m][cp] = v_w[((size_t)sk * 128 + 32 * a + m) * 128 + cp];
    }
    {
        float p = 0.f;
        for (int e = t; e < 2048; e += 256) p += sc[e];
        red[t] = p; __syncthreads();
        for (int off = 128; off > 0; off >>= 1) {
            if (t < off) red[t] += red[t + off];
            __syncthreads();
        }
        if (t == 0) s_mu = red[0] * (1.f / 2048.f);
        __syncthreads();
    }
    {
        const float mu = s_mu;
        float p = 0.f;
        for (int e = t; e < 2048; e += 256) { const float z = sc[e] - mu; p += z * z; }
        red[t] = p; __syncthreads();
        for (int off = 128; off > 0; off >>= 1) {
            if (t < off) red[t] += red[t + off];
            __syncthreads();
        }
        if (t == 0) s_rs = rsqrtf(red[0] * (1.f / 2048.f) + 1e-5f);
        __syncthreads();
    }
    const float mu = s_mu, rs = s_rs;
    const int r = t >> 4, l = t & 15;
    {
        float m = -1e30f;
#pragma unroll
        for (int j = 0; j < 8; ++j) {
            const float z = (sc[r * 128 + l + j * 16] - mu) * rs;
            m = fmaxf(m, z);
        }
        rowred[t] = m; __syncthreads();
        if (l == 0) {
            float m2 = rowred[r * 16];
            for (int j = 1; j < 16; ++j) m2 = fmaxf(m2, rowred[r * 16 + j]);
            rowmax[r] = m2;
        }
        __syncthreads();
    }
    {
        float p = 0.f;
#pragma unroll
        for (int j = 0; j < 8; ++j) {
            const float z = (sc[r * 128 + l + j * 16] - mu) * rs;
            p += expf(z - rowmax[r]);
        }
        rowred[t] = p; __syncthreads();
        if (l == 0) {
            float p2 = 0.f;
            for (int j = 0; j < 16; ++j) p2 += rowred[r * 16 + j];
            rowsum[r] = p2;
        }
        __syncthreads();
    }
    {
        float vals[8];
#pragma unroll
        for (int j = 0; j < 8; ++j) {
            const float z = (sc[r * 128 + l + j * 16] - mu) * rs;
            vals[j] = expf(z - rowmax[r]) / rowsum[r];
        }
        __syncthreads();
#pragma unroll
        for (int j = 0; j < 8; ++j) sc[r * 128 + l + j * 16] = vals[j];
        __syncthreads();
    }
    for (int e = t; e < 8192; e += 256) {
        const int sk = e >> 11, r2 = (e >> 7) & 15, cp = e & 127;
        float w = 0.f;
#pragma unroll
        for (int m = 0; m < 32; ++m)
            w = fmaf(sc[r2 * 128 + 4 * m + sk], kv[sk][m][cp], w);
        wEff[((size_t)(b * 4 + sk) * 64 + (a * 16 + r2)) * 128 + cp] = w;
    }
}

// ---------------------------------------------------------------------------
// K2c: wFinal. grid (s=4, b=4), 256 threads.
// ---------------------------------------------------------------------------
__global__ __launch_bounds__(256) void k2c(const float* __restrict__ out_w,
                                           const float* __restrict__ bn_gamma,
                                           const float* __restrict__ bn_var,
                                           const float* __restrict__ wEff,
                                           float* __restrict__ wFinal) {
    const int s = blockIdx.x, b = blockIdx.y;
    const int t = threadIdx.x;
    __shared__ float we[64][128];
    for (int idx = t; idx < 8192; idx += 256) {
        const int j = idx >> 7, cp = idx & 127;
        we[j][cp] = wEff[((size_t)(b * 4 + s) * 64 + j) * 128 + cp];
    }
    __syncthreads();
    for (int e = t; e < 2048; e += 256) {
        const int o = e >> 7, cp = e & 127;
        float w = 0.f;
#pragma unroll 16
        for (int j = 0; j < 64; ++j)
            w = fmaf(out_w[o * 64 + j], we[j][cp], w);
        const float scale = bn_gamma[o] * rsqrtf(bn_var[o] + 1e-5f);
        wFinal[((size_t)(b * 4 + s) * 16 + o) * 128 + cp] = w * scale;
    }
}

// ---------------------------------------------------------------------------
// K3: out = relu( sum_s wFinal_s·sur_s + bias ). grid (128, b=4), 256 thr.
// ---------------------------------------------------------------------------
__global__ __launch_bounds__(256) void k3_out(const float* __restrict__ cen,
                                              const float* __restrict__ wFinal,
                                              const float* __restrict__ bn_gamma,
                                              const float* __restrict__ bn_beta,
                                              const float* __restrict__ bn_mean,
                                              const float* __restrict__ bn_var,
                                              float* __restrict__ out) {
    const int by = blockIdx.x;
    const int b  = blockIdx.y;
    const int t  = threadIdx.x;
    __shared__ __align__(16) float wf[NS * CSUR * 16];
    __shared__ __align__(16) float wc[16 * 16];

    for (int e = t; e < NS * CSUR * 16; e += 256) {
        const int s = e >> 11, cp = (e >> 4) & 127, o = e & 15;
        wf[e] = wFinal[((size_t)(b * NS + s) * 16 + o) * CSUR + cp];
    }
    __syncthreads();
    {
        const int cin = t >> 4, o = t & 15;
        float sum = 0.f;
#pragma unroll
        for (int s = 0; s < NS; ++s)
#pragma unroll
            for (int k = 0; k < 8; ++k)
                sum += wf[(s * CSUR + k * 16 + cin) * 16 + o];
        wc[cin * 16 + o] = sum;
    }
    __syncthreads();

    const int x0 = t & 127;
    const int x1 = x0 + 128;
    const int y  = by * 2 + (t >> 7);
    const float* cb = cen + (size_t)b * CIN * AREA;

    float acc0[16], acc1[16];
#pragma unroll
    for (int o = 0; o < 16; ++o) { acc0[o] = 0.f; acc1[o] = 0.f; }

    for (int s = 0; s < NS; ++s) {
        const int d = 1 << s;
        for (int k = 0; k < 8; ++k) {
            const int ry  = refl(y + c_dy[k] * d);
            const int rx0 = refl(x0 + c_dx[k] * d);
            const int rx1 = refl(x1 + c_dx[k] * d);
            const float* crow = cb + ry * WW;
#pragma unroll
            for (int cin = 0; cin < 16; ++cin) {
                const float v0 = crow[cin * AREA + rx0];
                const float v1 = crow[cin * AREA + rx1];
                const float4* w4 = reinterpret_cast<const float4*>(&wf[(s * CSUR + k * 16 + cin) * 16]);
#pragma unroll
                for (int oq = 0; oq < 4; ++oq) {
                    const float4 w = w4[oq];
                    acc0[oq*4+0] = fmaf(w.x, v0, acc0[oq*4+0]); acc1[oq*4+0] = fmaf(w.x, v1, acc1[oq*4+0]);
                    acc0[oq*4+1] = fmaf(w.y, v0, acc0[oq*4+1]); acc1[oq*4+1] = fmaf(w.y, v1, acc1[oq*4+1]);
                    acc0[oq*4+2] = fmaf(w.z, v0, acc0[oq*4+2]); acc1[oq*4+2] = fmaf(w.z, v1, acc1[oq*4+2]);
                    acc0[oq*4+3] = fmaf(w.w, v0, acc0[oq*4+3]); acc1[oq*4+3] = fmaf(w.w, v1, acc1[oq*4+3]);
                }
            }
        }
    }
    {
        const float* crow = cb + y * WW;
#pragma unroll
        for (int cin = 0; cin < 16; ++cin) {
            const float v0 = crow[cin * AREA + x0];
            const float v1 = crow[cin * AREA + x1];
            const float4* w4 = reinterpret_cast<const float4*>(&wc[cin * 16]);
#pragma unroll
            for (int oq = 0; oq < 4; ++oq) {
                const float4 w = w4[oq];
                acc0[oq*4+0] = fmaf(-w.x, v0, acc0[oq*4+0]); acc1[oq*4+0] = fmaf(-w.x, v1, acc1[oq*4+0]);
                acc0[oq*4+1] = fmaf(-w.y, v0, acc0[oq*4+1]); acc1[oq*4+1] = fmaf(-w.y, v1, acc1[oq*4+1]);
                acc0[oq*4+2] = fmaf(-w.z, v0, acc0[oq*4+2]); acc1[oq*4+2] = fmaf(-w.z, v1, acc1[oq*4+2]);
                acc0[oq*4+3] = fmaf(-w.w, v0, acc0[oq*4+3]); acc1[oq*4+3] = fmaf(-w.w, v1, acc1[oq*4+3]);
            }
        }
    }
#pragma unroll
    for (int o = 0; o < 16; ++o) {
        const float scale = bn_gamma[o] * rsqrtf(bn_var[o] + 1e-5f);
        const float bias  = bn_beta[o] - bn_mean[o] * scale;
        const float r0 = fmaxf(acc0[o] + bias, 0.f);
        const float r1 = fmaxf(acc1[o] + bias, 0.f);
        out[((size_t)(b * 16 + o) * HH + y) * WW + x0] = r0;
        out[((size_t)(b * 16 + o) * HH + y) * WW + x1] = r1;
    }
}

// ---------------------------------------------------------------------------
extern "C" void kernel_launch(void* const* d_in, const int* in_sizes, int n_in,
                              void* d_out, int out_size, void* d_ws, size_t ws_size,
                              hipStream_t stream) {
    const float* cen      = (const float*)d_in[0];
    const float* q_w      = (const float*)d_in[1];
    const float* k_w      = (const float*)d_in[2];
    const float* v_w      = (const float*)d_in[3];
    const float* out_w    = (const float*)d_in[4];
    const float* bn_gamma = (const float*)d_in[5];
    const float* bn_beta  = (const float*)d_in[6];
    const float* bn_mean  = (const float*)d_in[7];
    const float* bn_var   = (const float*)d_in[8];
    float* out = (float*)d_out;

    char* ws = (char*)d_ws;
    const size_t PART_BYTES  = (size_t)4 * 16 * 20736 * 4;   // 5,308,416
    const size_t GFULL_BYTES = (size_t)16 * 20736 * 4;       // 1,327,104
    const size_t A_BYTES     = (size_t)16 * 64 * 128 * 4;    //   524,288
    const size_t NK_BYTES    = (size_t)16 * 128 * 4;         //     8,192
    const size_t NQ_BYTES    = (size_t)4 * 64 * 4;           //     1,024
    const size_t WEFF_BYTES  = (size_t)16 * 64 * 128 * 4;    //   524,288

    float* part  = (float*)(ws);
    float* Gfull = (float*)(ws + PART_BYTES);
    float* A     = (float*)(ws + PART_BYTES + GFULL_BYTES);
    float* normK = (float*)(ws + PART_BYTES + GFULL_BYTES + A_BYTES);
    float* normQ = (float*)(ws + PART_BYTES + GFULL_BYTES + A_BYTES + NK_BYTES);
    float* wEff  = (float*)(ws + PART_BYTES + GFULL_BYTES + A_BYTES + NK_BYTES + NQ_BYTES);
    float* wFin  = (float*)(ws + PART_BYTES + GFULL_BYTES + A_BYTES + NK_BYTES + NQ_BYTES + WEFF_BYTES);

    (void)hipMemsetAsync(part, 0, PART_BYTES, stream);
    (void)hipMemsetAsync(normK, 0, NK_BYTES, stream);
    k1_gram<<<dim3(64, 4, 4), 256, 0, stream>>>(cen, part);
    k1c<<<dim3(4, 4, 9), 256, 0, stream>>>(part, q_w, Gfull, A, normQ);
    k2n<<<dim3(4, 16, 2), 256, 0, stream>>>(k_w, Gfull, normK);
    k2b<<<dim3(4, 4), 256, 0, stream>>>(k_w, v_w, A, normK, normQ, wEff);
    k2c<<<dim3(4, 4), 256, 0, stream>>>(out_w, bn_gamma, bn_var, wEff, wFin);
    k3_out<<<dim3(128, 4), 256, 0, stream>>>(cen, wFin, bn_gamma, bn_beta,
                                             bn_mean, bn_var, out);
}

// Round 11
// 304.784 us; speedup vs baseline: 1.3757x; 1.0235x over previous
//
#include <hip/hip_runtime.h>
#include <hip/hip_bf16.h>
#include <math.h>

#define HH 256
#define WW 256
#define AREA 65536
#define CIN 16
#define NS 4
#define CSUR 128
#define NEXT 144
#define NPAIR 45

typedef __attribute__((ext_vector_type(8))) short bf16x8;
typedef __attribute__((ext_vector_type(4))) float f32x4;

__constant__ int c_dy[8] = {-1,-1,-1, 0, 0, 1, 1, 1};
__constant__ int c_dx[8] = {-1, 0, 1,-1, 1,-1, 0, 1};

__device__ constexpr int CTI[NPAIR] = {
    0, 1,1, 2,2,2, 3,3,3,3, 4,4,4,4,4,
    5,5,5,5,5,5, 6,6,6,6,6,6,6, 7,7,7,7,7,7,7,7,
    8,8,8,8,8,8,8,8,8};
__device__ constexpr int CTJ[NPAIR] = {
    0, 0,1, 0,1,2, 0,1,2,3, 0,1,2,3,4,
    0,1,2,3,4,5, 0,1,2,3,4,5,6, 0,1,2,3,4,5,6,7,
    0,1,2,3,4,5,6,7,8};

__device__ __forceinline__ int refl(int v) {
    return v < 0 ? -v : (v > 255 ? 510 - v : v);
}

// pack 2 floats to bf16x2 via HW cvt_pk (RNE)
__device__ __forceinline__ unsigned pkbf(float a, float b) {
    __hip_bfloat162 h = __float22bfloat162_rn(make_float2(a, b));
    unsigned r;
    __builtin_memcpy(&r, &h, 4);
    return r;
}

// write hi+lo pair into swizzled row: row c = 32 uints [hi g0..3 | lo g4..7],
// group g stored at physical slot g ^ (c&7).
__device__ __forceinline__ void wp(unsigned* __restrict__ m,
                                   int c, int pxp, float a, float b) {
    const int base = c * 32, sw = c & 7, gi = pxp >> 2, e = pxp & 3;
    const unsigned h = pkbf(a, b);
    m[base + ((gi ^ sw) << 2) + e] = h;
    const float fa = __builtin_bit_cast(float, h << 16);
    const float fb = __builtin_bit_cast(float, h & 0xFFFF0000u);
    m[base + (((4 + gi) ^ sw) << 2) + e] = pkbf(a - fa, b - fb);
}

// stage one kstep (32 pixels: row y, cols x0..x0+31)
__device__ __forceinline__ void stage_tile(unsigned* __restrict__ m,
                                           const float* __restrict__ base,
                                           int y, int x0, int cin, int pxp, int d) {
    constexpr int DY[8] = {-1,-1,-1, 0, 0, 1, 1, 1};
    constexpr int DX[8] = {-1, 0, 1,-1, 1,-1, 0, 1};
    const int x = x0 + 2 * pxp;
    const float2 cv = *(const float2*)(base + y * WW + x);
    wp(m, cin, pxp, cv.x, cv.y);                  // center rows 0..15
#pragma unroll
    for (int kk = 0; kk < 8; ++kk) {
        const int ys  = refl(y + DY[kk] * d);
        const int xs0 = refl(x + DX[kk] * d);
        const int xs1 = refl(x + 1 + DX[kk] * d);
        const float* row = base + ys * WW;
        wp(m, 16 + kk * 16 + cin, pxp, row[xs0] - cv.x, row[xs1] - cv.y);
    }
}

// ---------------------------------------------------------------------------
// K1: diff Gram via compensated bf16 MFMA, 4 waves, K=32 tiles, SINGLE LDS
// buffer (18.4 KB) for occupancy. grid (64 chunks x 4 rows, s=4, b=4), 256 thr.
// ---------------------------------------------------------------------------
__global__ __launch_bounds__(256) void k1_gram(const float* __restrict__ cen,
                                               float* __restrict__ part) {
    const int chunk = blockIdx.x;          // 0..63 -> 4 rows each
    const int s = blockIdx.y;
    const int b = blockIdx.z;
    const int d = 1 << s;
    const int t = threadIdx.x;
    const int lane = t & 63, wid = t >> 6;
    const int lr = lane & 15, lg = lane >> 4;
    const int cin = t >> 4, pxp = t & 15;
    const int y0 = chunk * 4;
    const float* base = cen + ((size_t)b * CIN + cin) * AREA;

    __shared__ unsigned lds[NEXT * 32];    // 18,432 B

    const int ghi = ((lg ^ (lr & 7)) << 2);
    const int glo = (((4 + lg) ^ (lr & 7)) << 2);

    f32x4 acc[12];
#pragma unroll
    for (int i = 0; i < 12; ++i) acc[i] = (f32x4){0.f, 0.f, 0.f, 0.f};

    for (int st = 0; st < 32; ++st) {
        stage_tile(lds, base, y0 + (st >> 3), (st & 7) * 32, cin, pxp, d);
        __syncthreads();
        bf16x8 fh[9], fl[9];
#pragma unroll
        for (int tt = 0; tt < 9; ++tt) {
            const int rb = (tt * 16 + lr) * 32;
            fh[tt] = *(const bf16x8*)(lds + rb + ghi);
            fl[tt] = *(const bf16x8*)(lds + rb + glo);
        }
        __syncthreads();   // lgkm drained before barrier -> frags safely in regs
#pragma unroll
        for (int p = 0; p < NPAIR; ++p) {
            if ((p & 3) == wid) {
                const int i = CTI[p], j = CTJ[p], a = p >> 2;
                acc[a] = __builtin_amdgcn_mfma_f32_16x16x32_bf16(fh[i], fh[j], acc[a], 0, 0, 0);
                acc[a] = __builtin_amdgcn_mfma_f32_16x16x32_bf16(fh[i], fl[j], acc[a], 0, 0, 0);
                acc[a] = __builtin_amdgcn_mfma_f32_16x16x32_bf16(fl[i], fh[j], acc[a], 0, 0, 0);
            }
        }
    }

    float* tb = part + (size_t)((chunk & 3) * 16 + b * 4 + s) * 20736;
#pragma unroll
    for (int p = 0; p < NPAIR; ++p) {
        if ((p & 3) == wid) {
            const int gi0 = CTI[p] * 16 + lg * 4;
            const int gj  = CTJ[p] * 16 + lr;
            const f32x4 a = acc[p >> 2];
#pragma unroll
            for (int r = 0; r < 4; ++r)
                atomicAdd(&tb[(gi0 + r) * 144 + gj], a[r]);
        }
    }
}

// ---------------------------------------------------------------------------
// K1c: per 16-row stripe: sum 4 partials + mirror -> Gfull rows; A-slice;
// normQ (z==0,s==0). grid (s=4, b=4, z=9), 256 threads.
// ---------------------------------------------------------------------------
__global__ __launch_bounds__(256) void k1c(const float* __restrict__ part,
                                           const float* __restrict__ q_w,
                                           float* __restrict__ Gfull,
                                           float* __restrict__ A,
                                           float* __restrict__ normQ) {
    const int s = blockIdx.x, b = blockIdx.y, z = blockIdx.z, bs = b * 4 + s;
    const int t = threadIdx.x;
    const int i0 = z * 16;
    __shared__ float Ts[16][148];
    const float* p0 = part + (size_t)(0 * 16 + bs) * 20736;
    const float* p1 = part + (size_t)(1 * 16 + bs) * 20736;
    const float* p2 = part + (size_t)(2 * 16 + bs) * 20736;
    const float* p3 = part + (size_t)(3 * 16 + bs) * 20736;
    for (int e = t; e < 16 * 144; e += 256) {
        const int il = e / 144, j = e - il * 144;
        const int i = i0 + il;
        const int src = (i >= j) ? (i * 144 + j) : (j * 144 + i);
        Ts[il][j] = p0[src] + p1[src] + p2[src] + p3[src];
    }
    __syncthreads();
    float* go = Gfull + (size_t)bs * 20736 + (size_t)i0 * 144;
    for (int e = t; e < 16 * 144; e += 256) {
        const int il = e / 144, j = e - il * 144;
        go[e] = Ts[il][j];
    }
    if (z >= 1) {
        for (int e = t; e < 1024; e += 256) {
            const int il = e >> 6, jq = e & 63;
            const float* qr = q_w + jq * 16;
            float aa = 0.f;
#pragma unroll
            for (int c = 0; c < 16; ++c) aa = fmaf(qr[c], Ts[il][c], aa);
            A[((size_t)bs * 64 + jq) * 128 + (i0 - 16 + il)] = aa;
        }
    }
    if (z == 0 && s == 0 && t < 64) {
        float nq = 0.f;
#pragma unroll
        for (int c1 = 0; c1 < 16; ++c1) {
            float ra = 0.f;
#pragma unroll
            for (int c2 = 0; c2 < 16; ++c2)
                ra = fmaf(q_w[t * 16 + c2], Ts[c1][c2], ra);
            nq = fmaf(q_w[t * 16 + c1], ra, nq);
        }
        normQ[b * 64 + t] = nq;
    }
}

// ---------------------------------------------------------------------------
// K2n: normK[bs][ck] = k_row·H·k_rowT, split (32 ck) x (64 i) per block.
// grid (ckg=4, bs=16, ih=2), 256 threads.
// ---------------------------------------------------------------------------
__global__ __launch_bounds__(256) void k2n(const float* __restrict__ k_w,
                                           const float* __restrict__ Gfull,
                                           float* __restrict__ normK) {
    const int ckg = blockIdx.x, bs = blockIdx.y, ih = blockIdx.z;
    const int s = bs & 3;
    const int t = threadIdx.x;
    __shared__ float kS[32][129];
    __shared__ float Hs[64][129];
    __shared__ float red[256];
    for (int e = t; e < 4096; e += 256) {
        const int r = e >> 7, j = e & 127;
        kS[r][j] = k_w[(size_t)(s * 128 + ckg * 32 + r) * 128 + j];
    }
    for (int e = t; e < 8192; e += 256) {
        const int r = e >> 7, j = e & 127;
        Hs[r][j] = Gfull[(size_t)bs * 20736 + (16 + ih * 64 + r) * 144 + 16 + j];
    }
    __syncthreads();
    const int ckl = t & 31, p = t >> 5;
    float m[8];
#pragma unroll
    for (int i = 0; i < 8; ++i) m[i] = 0.f;
    for (int j = 0; j < 128; ++j) {
        const float kv = kS[ckl][j];
#pragma unroll
        for (int i = 0; i < 8; ++i) m[i] = fmaf(Hs[p * 8 + i][j], kv, m[i]);
    }
    float prt = 0.f;
#pragma unroll
    for (int i = 0; i < 8; ++i)
        prt = fmaf(kS[ckl][ih * 64 + p * 8 + i], m[i], prt);
    red[t] = prt;
    __syncthreads();
    if (t < 32) {
        float s8 = 0.f;
#pragma unroll
        for (int q = 0; q < 8; ++q) s8 += red[q * 32 + t];
        atomicAdd(&normK[(size_t)bs * 128 + ckg * 32 + t], s8);
    }
}

// ---------------------------------------------------------------------------
// K2s: normalized scores -> scWs. grid (a=4, b=4, rq=4), 256 threads.
// sc layout matches k2b: sc[r*128 + 4*ckl + sk], r = rq*4 + i.
// ---------------------------------------------------------------------------
__global__ __launch_bounds__(256) void k2s(const float* __restrict__ k_w,
                                           const float* __restrict__ A,
                                           const float* __restrict__ normK,
                                           const float* __restrict__ normQ,
                                           float* __restrict__ scWs) {
    const int a = blockIdx.x, b = blockIdx.y, rq = blockIdx.z;
    const int t = threadIdx.x;
    __shared__ float AS[16][132];
    for (int e = t; e < 2048; e += 256) {
        const int row = e >> 7, cp = e & 127;   // row = sk*4 + i
        const int sk = row >> 2, i = row & 3;
        const int jq = i * 16 + 4 * a + rq;
        AS[row][cp] = A[((size_t)(b * 4 + sk) * 64 + jq) * 128 + cp];
    }
    __syncthreads();
    for (int e = t; e < 512; e += 256) {
        const int sk = e >> 7, i = (e >> 5) & 3, ckl = e & 31;
        const int jq = i * 16 + 4 * a + rq;
        const float4* Ar = (const float4*)(&AS[sk * 4 + i][0]);
        const float4* kr = (const float4*)(k_w + ((size_t)sk * 128 + 32 * a + ckl) * 128);
        float4 pv = {0.f, 0.f, 0.f, 0.f};
#pragma unroll 8
        for (int jj = 0; jj < 32; ++jj) {
            const float4 h = Ar[jj], k4 = kr[jj];
            pv.x = fmaf(h.x, k4.x, pv.x);
            pv.y = fmaf(h.y, k4.y, pv.y);
            pv.z = fmaf(h.z, k4.z, pv.z);
            pv.w = fmaf(h.w, k4.w, pv.w);
        }
        const float dot = pv.x + pv.y + pv.z + pv.w;
        const float qn = fmaxf(sqrtf(fmaxf(normQ[b * 64 + jq], 0.f)), 1e-12f);
        const float kn = fmaxf(sqrtf(fmaxf(normK[(size_t)(b * 4 + sk) * 128 + 32 * a + ckl], 0.f)), 1e-12f);
        const int r = rq * 4 + i;
        scWs[((size_t)(b * 4 + a)) * 2048 + r * 128 + 4 * ckl + sk] =
            dot / (qn * kn * 256.0f);
    }
}

// ---------------------------------------------------------------------------
// K2b: instance norm -> softmax -> wEff (scores precomputed by k2s).
// grid (a=4, b=4), 256 threads.
// ---------------------------------------------------------------------------
__global__ __launch_bounds__(256) void k2b(const float* __restrict__ v_w,
                                           const float* __restrict__ scWs,
                                           float* __restrict__ wEff) {
    const int a = blockIdx.x, b = blockIdx.y;
    const int t = threadIdx.x;
    __shared__ float kv[4][32][132];
    __shared__ float sc[2048];
    __shared__ float red[256];
    __shared__ float rowred[256];
    __shared__ float rowmax[16], rowsum[16];
    __shared__ float s_mu, s_rs;

    for (int idx = t; idx < 2048; idx += 256)
        sc[idx] = scWs[((size_t)(b * 4 + a)) * 2048 + idx];
    for (int idx = t; idx < 16384; idx += 256) {
        const int sk = idx >> 12, m = (idx >> 7) & 31, cp = idx & 127;
        kv[sk][m][cp] = v_w[((size_t)sk * 128 + 32 * a + m) * 128 + cp];
    }
    __syncthreads();
    {
        float p = 0.f;
        for (int e = t; e < 2048; e += 256) p += sc[e];
        red[t] = p; __syncthreads();
        for (int off = 128; off > 0; off >>= 1) {
            if (t < off) red[t] += red[t + off];
            __syncthreads();
        }
        if (t == 0) s_mu = red[0] * (1.f / 2048.f);
        __syncthreads();
    }
    {
        const float mu = s_mu;
        float p = 0.f;
        for (int e = t; e < 2048; e += 256) { const float z = sc[e] - mu; p += z * z; }
        red[t] = p; __syncthreads();
        for (int off = 128; off > 0; off >>= 1) {
            if (t < off) red[t] += red[t + off];
            __syncthreads();
        }
        if (t == 0) s_rs = rsqrtf(red[0] * (1.f / 2048.f) + 1e-5f);
        __syncthreads();
    }
    const float mu = s_mu, rs = s_rs;
    const int r = t >> 4, l = t & 15;
    {
        float m = -1e30f;
#pragma unroll
        for (int j = 0; j < 8; ++j) {
            const float z = (sc[r * 128 + l + j * 16] - mu) * rs;
            m = fmaxf(m, z);
        }
        rowred[t] = m; __syncthreads();
        if (l == 0) {
            float m2 = rowred[r * 16];
            for (int j = 1; j < 16; ++j) m2 = fmaxf(m2, rowred[r * 16 + j]);
            rowmax[r] = m2;
        }
        __syncthreads();
    }
    {
        float p = 0.f;
#pragma unroll
        for (int j = 0; j < 8; ++j) {
            const float z = (sc[r * 128 + l + j * 16] - mu) * rs;
            p += expf(z - rowmax[r]);
        }
        rowred[t] = p; __syncthreads();
        if (l == 0) {
            float p2 = 0.f;
            for (int j = 0; j < 16; ++j) p2 += rowred[r * 16 + j];
            rowsum[r] = p2;
        }
        __syncthreads();
    }
    {
        float vals[8];
#pragma unroll
        for (int j = 0; j < 8; ++j) {
            const float z = (sc[r * 128 + l + j * 16] - mu) * rs;
            vals[j] = expf(z - rowmax[r]) / rowsum[r];
        }
        __syncthreads();
#pragma unroll
        for (int j = 0; j < 8; ++j) sc[r * 128 + l + j * 16] = vals[j];
        __syncthreads();
    }
    for (int e = t; e < 8192; e += 256) {
        const int sk = e >> 11, r2 = (e >> 7) & 15, cp = e & 127;
        float w = 0.f;
#pragma unroll
        for (int m = 0; m < 32; ++m)
            w = fmaf(sc[r2 * 128 + 4 * m + sk], kv[sk][m][cp], w);
        wEff[((size_t)(b * 4 + sk) * 64 + (a * 16 + r2)) * 128 + cp] = w;
    }
}

// ---------------------------------------------------------------------------
// K2c: wFinal. grid (s=4, b=4), 256 threads.
// ---------------------------------------------------------------------------
__global__ __launch_bounds__(256) void k2c(const float* __restrict__ out_w,
                                           const float* __restrict__ bn_gamma,
                                           const float* __restrict__ bn_var,
                                           const float* __restrict__ wEff,
                                           float* __restrict__ wFinal) {
    const int s = blockIdx.x, b = blockIdx.y;
    const int t = threadIdx.x;
    __shared__ float we[64][128];
    for (int idx = t; idx < 8192; idx += 256) {
        const int j = idx >> 7, cp = idx & 127;
        we[j][cp] = wEff[((size_t)(b * 4 + s) * 64 + j) * 128 + cp];
    }
    __syncthreads();
    for (int e = t; e < 2048; e += 256) {
        const int o = e >> 7, cp = e & 127;
        float w = 0.f;
#pragma unroll 16
        for (int j = 0; j < 64; ++j)
            w = fmaf(out_w[o * 64 + j], we[j][cp], w);
        const float scale = bn_gamma[o] * rsqrtf(bn_var[o] + 1e-5f);
        wFinal[((size_t)(b * 4 + s) * 16 + o) * 128 + cp] = w * scale;
    }
}

// ---------------------------------------------------------------------------
// K3: out = relu( sum_s wFinal_s·sur_s + bias ). grid (128, b=4), 256 thr.
// ---------------------------------------------------------------------------
__global__ __launch_bounds__(256) void k3_out(const float* __restrict__ cen,
                                              const float* __restrict__ wFinal,
                                              const float* __restrict__ bn_gamma,
                                              const float* __restrict__ bn_beta,
                                              const float* __restrict__ bn_mean,
                                              const float* __restrict__ bn_var,
                                              float* __restrict__ out) {
    const int by = blockIdx.x;
    const int b  = blockIdx.y;
    const int t  = threadIdx.x;
    __shared__ __align__(16) float wf[NS * CSUR * 16];
    __shared__ __align__(16) float wc[16 * 16];

    for (int e = t; e < NS * CSUR * 16; e += 256) {
        const int s = e >> 11, cp = (e >> 4) & 127, o = e & 15;
        wf[e] = wFinal[((size_t)(b * NS + s) * 16 + o) * CSUR + cp];
    }
    __syncthreads();
    {
        const int cin = t >> 4, o = t & 15;
        float sum = 0.f;
#pragma unroll
        for (int s = 0; s < NS; ++s)
#pragma unroll
            for (int k = 0; k < 8; ++k)
                sum += wf[(s * CSUR + k * 16 + cin) * 16 + o];
        wc[cin * 16 + o] = sum;
    }
    __syncthreads();

    const int x0 = t & 127;
    const int x1 = x0 + 128;
    const int y  = by * 2 + (t >> 7);
    const float* cb = cen + (size_t)b * CIN * AREA;

    float acc0[16], acc1[16];
#pragma unroll
    for (int o = 0; o < 16; ++o) { acc0[o] = 0.f; acc1[o] = 0.f; }

    for (int s = 0; s < NS; ++s) {
        const int d = 1 << s;
        for (int k = 0; k < 8; ++k) {
            const int ry  = refl(y + c_dy[k] * d);
            const int rx0 = refl(x0 + c_dx[k] * d);
            const int rx1 = refl(x1 + c_dx[k] * d);
            const float* crow = cb + ry * WW;
#pragma unroll
            for (int cin = 0; cin < 16; ++cin) {
                const float v0 = crow[cin * AREA + rx0];
                const float v1 = crow[cin * AREA + rx1];
                const float4* w4 = reinterpret_cast<const float4*>(&wf[(s * CSUR + k * 16 + cin) * 16]);
#pragma unroll
                for (int oq = 0; oq < 4; ++oq) {
                    const float4 w = w4[oq];
                    acc0[oq*4+0] = fmaf(w.x, v0, acc0[oq*4+0]); acc1[oq*4+0] = fmaf(w.x, v1, acc1[oq*4+0]);
                    acc0[oq*4+1] = fmaf(w.y, v0, acc0[oq*4+1]); acc1[oq*4+1] = fmaf(w.y, v1, acc1[oq*4+1]);
                    acc0[oq*4+2] = fmaf(w.z, v0, acc0[oq*4+2]); acc1[oq*4+2] = fmaf(w.z, v1, acc1[oq*4+2]);
                    acc0[oq*4+3] = fmaf(w.w, v0, acc0[oq*4+3]); acc1[oq*4+3] = fmaf(w.w, v1, acc1[oq*4+3]);
                }
            }
        }
    }
    {
        const float* crow = cb + y * WW;
#pragma unroll
        for (int cin = 0; cin < 16; ++cin) {
            const float v0 = crow[cin * AREA + x0];
            const float v1 = crow[cin * AREA + x1];
            const float4* w4 = reinterpret_cast<const float4*>(&wc[cin * 16]);
#pragma unroll
            for (int oq = 0; oq < 4; ++oq) {
                const float4 w = w4[oq];
                acc0[oq*4+0] = fmaf(-w.x, v0, acc0[oq*4+0]); acc1[oq*4+0] = fmaf(-w.x, v1, acc1[oq*4+0]);
                acc0[oq*4+1] = fmaf(-w.y, v0, acc0[oq*4+1]); acc1[oq*4+1] = fmaf(-w.y, v1, acc1[oq*4+1]);
                acc0[oq*4+2] = fmaf(-w.z, v0, acc0[oq*4+2]); acc1[oq*4+2] = fmaf(-w.z, v1, acc1[oq*4+2]);
                acc0[oq*4+3] = fmaf(-w.w, v0, acc0[oq*4+3]); acc1[oq*4+3] = fmaf(-w.w, v1, acc1[oq*4+3]);
            }
        }
    }
#pragma unroll
    for (int o = 0; o < 16; ++o) {
        const float scale = bn_gamma[o] * rsqrtf(bn_var[o] + 1e-5f);
        const float bias  = bn_beta[o] - bn_mean[o] * scale;
        const float r0 = fmaxf(acc0[o] + bias, 0.f);
        const float r1 = fmaxf(acc1[o] + bias, 0.f);
        out[((size_t)(b * 16 + o) * HH + y) * WW + x0] = r0;
        out[((size_t)(b * 16 + o) * HH + y) * WW + x1] = r1;
    }
}

// ---------------------------------------------------------------------------
extern "C" void kernel_launch(void* const* d_in, const int* in_sizes, int n_in,
                              void* d_out, int out_size, void* d_ws, size_t ws_size,
                              hipStream_t stream) {
    const float* cen      = (const float*)d_in[0];
    const float* q_w      = (const float*)d_in[1];
    const float* k_w      = (const float*)d_in[2];
    const float* v_w      = (const float*)d_in[3];
    const float* out_w    = (const float*)d_in[4];
    const float* bn_gamma = (const float*)d_in[5];
    const float* bn_beta  = (const float*)d_in[6];
    const float* bn_mean  = (const float*)d_in[7];
    const float* bn_var   = (const float*)d_in[8];
    float* out = (float*)d_out;

    char* ws = (char*)d_ws;
    const size_t PART_BYTES  = (size_t)4 * 16 * 20736 * 4;   // 5,308,416
    const size_t GFULL_BYTES = (size_t)16 * 20736 * 4;       // 1,327,104
    const size_t A_BYTES     = (size_t)16 * 64 * 128 * 4;    //   524,288
    const size_t NK_BYTES    = (size_t)16 * 128 * 4;         //     8,192
    const size_t NQ_BYTES    = (size_t)4 * 64 * 4;           //     1,024
    const size_t SC_BYTES    = (size_t)16 * 2048 * 4;        //   131,072
    const size_t WEFF_BYTES  = (size_t)16 * 64 * 128 * 4;    //   524,288

    float* part  = (float*)(ws);
    float* Gfull = (float*)(ws + PART_BYTES);
    float* A     = (float*)(ws + PART_BYTES + GFULL_BYTES);
    float* normK = (float*)(ws + PART_BYTES + GFULL_BYTES + A_BYTES);
    float* normQ = (float*)(ws + PART_BYTES + GFULL_BYTES + A_BYTES + NK_BYTES);
    float* scWs  = (float*)(ws + PART_BYTES + GFULL_BYTES + A_BYTES + NK_BYTES + NQ_BYTES);
    float* wEff  = (float*)(ws + PART_BYTES + GFULL_BYTES + A_BYTES + NK_BYTES + NQ_BYTES + SC_BYTES);
    float* wFin  = (float*)(ws + PART_BYTES + GFULL_BYTES + A_BYTES + NK_BYTES + NQ_BYTES + SC_BYTES + WEFF_BYTES);

    (void)hipMemsetAsync(part, 0, PART_BYTES, stream);
    (void)hipMemsetAsync(normK, 0, NK_BYTES, stream);
    k1_gram<<<dim3(64, 4, 4), 256, 0, stream>>>(cen, part);
    k1c<<<dim3(4, 4, 9), 256, 0, stream>>>(part, q_w, Gfull, A, normQ);
    k2n<<<dim3(4, 16, 2), 256, 0, stream>>>(k_w, Gfull, normK);
    k2s<<<dim3(4, 4, 4), 256, 0, stream>>>(k_w, A, normK, normQ, scWs);
    k2b<<<dim3(4, 4), 256, 0, stream>>>(v_w, scWs, wEff);
    k2c<<<dim3(4, 4), 256, 0, stream>>>(out_w, bn_gamma, bn_var, wEff, wFin);
    k3_out<<<dim3(128, 4), 256, 0, stream>>>(cen, wFin, bn_gamma, bn_beta,
                                             bn_mean, bn_var, out);
}